// Round 1
// baseline (1927.904 us; speedup 1.0000x reference)
//
#include <hip/hip_runtime.h>
#include <hip/hip_bf16.h>

#define NCLS 16
#define NBOX 2048
#define NTOT (NCLS * NBOX)
#define SCORE_THRESH 0.05f
#define NMS_THRESH 0.5f
#define DETS_PER_IMG 100
#define BBOX_CLIP 4.135166556742356f  /* log(1000/16) */

// ---------------- Kernel 1: softmax score + box decode ----------------
__global__ __launch_bounds__(256) void decode_kernel(
    const float* __restrict__ logits,   // (NTOT, 2)
    const float* __restrict__ regr,     // (NTOT, 8)
    const float* __restrict__ props,    // (NBOX, 4)
    float* __restrict__ scores,         // (NTOT)
    float4* __restrict__ dec)           // (NTOT)
{
#pragma clang fp contract(off)
    int i = blockIdx.x * blockDim.x + threadIdx.x;
    if (i >= NTOT) return;

    float x0 = logits[2 * i + 0];
    float x1 = logits[2 * i + 1];
    float m = fmaxf(x0, x1);
    float e0 = expf(x0 - m);
    float e1 = expf(x1 - m);
    float score = e1 / (e0 + e1);
    scores[i] = score;

    int k = i & (NBOX - 1);
    float px1 = props[4 * k + 0];
    float py1 = props[4 * k + 1];
    float px2 = props[4 * k + 2];
    float py2 = props[4 * k + 3];

    float w  = px2 - px1 + 1.0f;
    float h  = py2 - py1 + 1.0f;
    float cx = px1 + 0.5f * w;
    float cy = py1 + 0.5f * h;

    float dx = regr[8 * i + 4] / 10.0f;
    float dy = regr[8 * i + 5] / 10.0f;
    float dw = fminf(regr[8 * i + 6] / 5.0f, BBOX_CLIP);
    float dh = fminf(regr[8 * i + 7] / 5.0f, BBOX_CLIP);

    float pcx = dx * w + cx;
    float pcy = dy * h + cy;
    float pw  = expf(dw) * w;
    float ph  = expf(dh) * h;

    float b0 = pcx - 0.5f * pw;
    float b1 = pcy - 0.5f * ph;
    float b2 = pcx + 0.5f * pw - 1.0f;
    float b3 = pcy + 0.5f * ph - 1.0f;

    b0 = fminf(fmaxf(b0, 0.0f), 1332.0f);
    b1 = fminf(fmaxf(b1, 0.0f), 799.0f);
    b2 = fminf(fmaxf(b2, 0.0f), 1332.0f);
    b3 = fminf(fmaxf(b3, 0.0f), 799.0f);

    dec[i] = make_float4(b0, b1, b2, b3);
}

// ---------------- Kernel 2: per-class bitonic sort ----------------
// key = (monotone_score_bits << 32) | (2047 - idx); invalid -> score part 0.
// Descending sort => stable emulation of jnp.argsort(-masked).
__global__ __launch_bounds__(256) void sort_kernel(
    const float* __restrict__ scores,
    unsigned long long* __restrict__ keys_out)
{
    int c = blockIdx.x;
    __shared__ unsigned long long sk[NBOX];
    const float* sc = scores + c * NBOX;

    for (int i = threadIdx.x; i < NBOX; i += blockDim.x) {
        float s = sc[i];
        unsigned int mono = 0u;
        if (s > SCORE_THRESH) {
            mono = __float_as_uint(s) | 0x80000000u;  // positive floats, keep order
        }
        sk[i] = ((unsigned long long)mono << 32) |
                (unsigned long long)(unsigned)(NBOX - 1 - i);
    }
    __syncthreads();

    for (int k = 2; k <= NBOX; k <<= 1) {
        for (int j = k >> 1; j > 0; j >>= 1) {
            for (int i = threadIdx.x; i < NBOX; i += blockDim.x) {
                int ixj = i ^ j;
                if (ixj > i) {
                    unsigned long long a = sk[i];
                    unsigned long long b = sk[ixj];
                    bool desc = ((i & k) == 0);
                    bool sw = desc ? (a < b) : (a > b);
                    if (sw) { sk[i] = b; sk[ixj] = a; }
                }
            }
            __syncthreads();
        }
    }

    for (int i = threadIdx.x; i < NBOX; i += blockDim.x)
        keys_out[c * NBOX + i] = sk[i];
}

// ---------------- Kernel 3: per-class greedy NMS ----------------
__global__ __launch_bounds__(256) void nms_kernel(
    const unsigned long long* __restrict__ keys,
    const float4* __restrict__ dec,
    int* __restrict__ keep)
{
#pragma clang fp contract(off)
    int c = blockIdx.x;
    __shared__ float sx1[NBOX], sy1[NBOX], sx2[NBOX], sy2[NBOX], sar[NBOX];
    __shared__ unsigned char ssup[NBOX];
    __shared__ unsigned char svalid[NBOX];
    __shared__ int sorig[NBOX];
    __shared__ int s_cur;

    for (int i = threadIdx.x; i < NBOX; i += blockDim.x) {
        unsigned long long key = keys[c * NBOX + i];
        int idx = (NBOX - 1) - (int)(key & 0xFFFFFFFFull);
        int orig = c * NBOX + idx;
        float4 b = dec[orig];
        sx1[i] = b.x; sy1[i] = b.y; sx2[i] = b.z; sy2[i] = b.w;
        sar[i] = (b.z - b.x) * (b.w - b.y);
        ssup[i] = 0;
        svalid[i] = ((unsigned)(key >> 32)) != 0u;
        sorig[i] = orig;
        keep[orig] = 0;
    }
    __syncthreads();

    int i = 0;
    while (true) {
        if (threadIdx.x == 0) {
            while (i < NBOX && (!svalid[i] || ssup[i])) i++;
            s_cur = i;
            if (i < NBOX) keep[sorig[i]] = 1;
        }
        __syncthreads();
        i = s_cur;
        if (i >= NBOX) break;

        float x1 = sx1[i], y1 = sy1[i], x2 = sx2[i], y2 = sy2[i], ar = sar[i];
        for (int j = i + 1 + threadIdx.x; j < NBOX; j += blockDim.x) {
            if (ssup[j]) continue;
            float lx = fmaxf(x1, sx1[j]);
            float ly = fmaxf(y1, sy1[j]);
            float rx = fminf(x2, sx2[j]);
            float ry = fminf(y2, sy2[j]);
            float w = fmaxf(rx - lx, 0.0f);
            float h = fmaxf(ry - ly, 0.0f);
            float inter = w * h;
            float iou = inter / (ar + sar[j] - inter + 1e-12f);
            if (iou > NMS_THRESH) ssup[j] = 1;
        }
        __syncthreads();
        i = s_cur + 1;
    }
}

// ---------------- Kernel 4: count + exact radix-select of kth score ----------------
__global__ __launch_bounds__(1024) void select_kernel(
    const int* __restrict__ keep,
    const float* __restrict__ scores,
    int* __restrict__ stats)   // stats[0]=n_det, stats[1]=kth bits
{
    __shared__ int hist[256];
    __shared__ int s_count;
    __shared__ unsigned s_prefix;
    __shared__ int s_rank;
    int tid = threadIdx.x;

    if (tid == 0) s_count = 0;
    __syncthreads();

    int cnt = 0;
    for (int i = tid; i < NTOT; i += 1024) cnt += keep[i];
    atomicAdd(&s_count, cnt);
    __syncthreads();
    int n_det = s_count;

    if (tid == 0) { s_prefix = 0u; s_rank = DETS_PER_IMG; }
    __syncthreads();

    if (n_det > DETS_PER_IMG) {
        for (int pass = 3; pass >= 0; pass--) {
            int shift = pass * 8;
            if (tid < 256) hist[tid] = 0;
            __syncthreads();
            unsigned pref = s_prefix;
            unsigned pmask = (pass == 3) ? 0u : (0xFFFFFFFFu << ((pass + 1) * 8));
            for (int i = tid; i < NTOT; i += 1024) {
                if (keep[i]) {
                    unsigned b = __float_as_uint(scores[i]);  // positive -> bit-monotone
                    if ((b & pmask) == pref)
                        atomicAdd(&hist[(b >> shift) & 0xFF], 1);
                }
            }
            __syncthreads();
            if (tid == 0) {
                int r = s_rank;
                for (int bin = 255; bin >= 0; bin--) {
                    int cd = hist[bin];
                    if (r <= cd) {
                        s_prefix = pref | ((unsigned)bin << shift);
                        s_rank = r;
                        break;
                    }
                    r -= cd;
                }
            }
            __syncthreads();
        }
    }

    if (tid == 0) { stats[0] = n_det; stats[1] = (int)s_prefix; }
}

// ---------------- Kernel 5: final outputs ----------------
__global__ __launch_bounds__(256) void write_kernel(
    const float* __restrict__ scores,
    const float4* __restrict__ dec,
    const int* __restrict__ keep,
    const int* __restrict__ stats,
    const int* __restrict__ ulabels,
    float* __restrict__ out)
{
    int i = blockIdx.x * blockDim.x + threadIdx.x;
    if (i >= NTOT) return;

    int n_det = stats[0];
    float kth = __uint_as_float((unsigned)stats[1]);
    float s = scores[i];
    bool kf = keep[i] && (n_det <= DETS_PER_IMG || s >= kth);

    float4 b = dec[i];
    float* o5 = out + (size_t)i * 5;
    if (kf) {
        o5[0] = b.x; o5[1] = b.y; o5[2] = b.z; o5[3] = b.w; o5[4] = s;
    } else {
        o5[0] = 0.0f; o5[1] = 0.0f; o5[2] = 0.0f; o5[3] = 0.0f; o5[4] = 0.0f;
    }

    int c = i >> 11;
    out[NTOT * 5 + i] = (float)ulabels[c];
    out[NTOT * 5 + NTOT + i] = kf ? 1.0f : 0.0f;
}

extern "C" void kernel_launch(void* const* d_in, const int* in_sizes, int n_in,
                              void* d_out, int out_size, void* d_ws, size_t ws_size,
                              hipStream_t stream) {
    (void)in_sizes; (void)n_in; (void)out_size; (void)ws_size;

    const float* class_logit    = (const float*)d_in[0];   // (NTOT,2)
    const float* box_regression = (const float*)d_in[1];   // (NTOT,8)
    const float* proposal_boxes = (const float*)d_in[2];   // (NBOX,4)
    const int*   unique_labels  = (const int*)d_in[3];     // (NCLS)

    char* ws = (char*)d_ws;
    float* scores            = (float*)ws;                                  // 131072 B
    float4* dec              = (float4*)(ws + 131072);                      // 524288 B
    unsigned long long* keys = (unsigned long long*)(ws + 131072 + 524288); // 262144 B
    int* keep                = (int*)(ws + 917504);                         // 131072 B
    int* stats               = (int*)(ws + 1048576);                        // 8 B

    float* out = (float*)d_out;

    decode_kernel<<<NTOT / 256, 256, 0, stream>>>(class_logit, box_regression,
                                                  proposal_boxes, scores, dec);
    sort_kernel<<<NCLS, 256, 0, stream>>>(scores, keys);
    nms_kernel<<<NCLS, 256, 0, stream>>>(keys, dec, keep);
    select_kernel<<<1, 1024, 0, stream>>>(keep, scores, stats);
    write_kernel<<<NTOT / 256, 256, 0, stream>>>(scores, dec, keep, stats,
                                                 unique_labels, out);
}

// Round 2
// 1525.118 us; speedup vs baseline: 1.2641x; 1.2641x over previous
//
#include <hip/hip_runtime.h>
#include <hip/hip_bf16.h>

#define NCLS 16
#define NBOX 2048
#define NTOT (NCLS * NBOX)
#define SCORE_THRESH 0.05f
#define NMS_THRESH 0.5f
#define DETS_PER_IMG 100
#define BBOX_CLIP 4.135166556742356f  /* log(1000/16) */

// IoU identical (op order) to the reference; symmetric in the two boxes.
__device__ __forceinline__ float iou_f(float x1, float y1, float x2, float y2, float ar,
                                       float X1, float Y1, float X2, float Y2, float AR) {
#pragma clang fp contract(off)
    float lx = fmaxf(x1, X1);
    float ly = fmaxf(y1, Y1);
    float rx = fminf(x2, X2);
    float ry = fminf(y2, Y2);
    float w = fmaxf(rx - lx, 0.0f);
    float h = fmaxf(ry - ly, 0.0f);
    float inter = w * h;
    return inter / (ar + AR - inter + 1e-12f);
}

// ---------------- Kernel 1: softmax score + box decode ----------------
__global__ __launch_bounds__(256) void decode_kernel(
    const float* __restrict__ logits,   // (NTOT, 2)
    const float* __restrict__ regr,     // (NTOT, 8)
    const float* __restrict__ props,    // (NBOX, 4)
    float* __restrict__ scores,         // (NTOT)
    float4* __restrict__ dec)           // (NTOT)
{
#pragma clang fp contract(off)
    int i = blockIdx.x * blockDim.x + threadIdx.x;
    if (i >= NTOT) return;

    float x0 = logits[2 * i + 0];
    float x1 = logits[2 * i + 1];
    float m = fmaxf(x0, x1);
    float e0 = expf(x0 - m);
    float e1 = expf(x1 - m);
    float score = e1 / (e0 + e1);
    scores[i] = score;

    int k = i & (NBOX - 1);
    float px1 = props[4 * k + 0];
    float py1 = props[4 * k + 1];
    float px2 = props[4 * k + 2];
    float py2 = props[4 * k + 3];

    float w  = px2 - px1 + 1.0f;
    float h  = py2 - py1 + 1.0f;
    float cx = px1 + 0.5f * w;
    float cy = py1 + 0.5f * h;

    float dx = regr[8 * i + 4] / 10.0f;
    float dy = regr[8 * i + 5] / 10.0f;
    float dw = fminf(regr[8 * i + 6] / 5.0f, BBOX_CLIP);
    float dh = fminf(regr[8 * i + 7] / 5.0f, BBOX_CLIP);

    float pcx = dx * w + cx;
    float pcy = dy * h + cy;
    float pw  = expf(dw) * w;
    float ph  = expf(dh) * h;

    float b0 = pcx - 0.5f * pw;
    float b1 = pcy - 0.5f * ph;
    float b2 = pcx + 0.5f * pw - 1.0f;
    float b3 = pcy + 0.5f * ph - 1.0f;

    b0 = fminf(fmaxf(b0, 0.0f), 1332.0f);
    b1 = fminf(fmaxf(b1, 0.0f), 799.0f);
    b2 = fminf(fmaxf(b2, 0.0f), 1332.0f);
    b3 = fminf(fmaxf(b3, 0.0f), 799.0f);

    dec[i] = make_float4(b0, b1, b2, b3);
}

// ---------------- Kernel 2: per-class bitonic sort ----------------
// key = (monotone_score_bits << 32) | (2047 - idx); invalid -> score part 0.
// Descending sort => stable emulation of jnp.argsort(-masked).
__global__ __launch_bounds__(256) void sort_kernel(
    const float* __restrict__ scores,
    unsigned long long* __restrict__ keys_out)
{
    int c = blockIdx.x;
    __shared__ unsigned long long sk[NBOX];
    const float* sc = scores + c * NBOX;

    for (int i = threadIdx.x; i < NBOX; i += blockDim.x) {
        float s = sc[i];
        unsigned int mono = 0u;
        if (s > SCORE_THRESH) {
            mono = __float_as_uint(s) | 0x80000000u;  // positive floats, keep order
        }
        sk[i] = ((unsigned long long)mono << 32) |
                (unsigned long long)(unsigned)(NBOX - 1 - i);
    }
    __syncthreads();

    for (int k = 2; k <= NBOX; k <<= 1) {
        for (int j = k >> 1; j > 0; j >>= 1) {
            for (int i = threadIdx.x; i < NBOX; i += blockDim.x) {
                int ixj = i ^ j;
                if (ixj > i) {
                    unsigned long long a = sk[i];
                    unsigned long long b = sk[ixj];
                    bool desc = ((i & k) == 0);
                    bool sw = desc ? (a < b) : (a > b);
                    if (sw) { sk[i] = b; sk[ixj] = a; }
                }
            }
            __syncthreads();
        }
    }

    for (int i = threadIdx.x; i < NBOX; i += blockDim.x)
        keys_out[c * NBOX + i] = sk[i];
}

// ---------------- Kernel 3: per-class blocked greedy NMS ----------------
// Chunks of 64 sorted boxes. Wave 0 resolves intra-chunk suppression with a
// wave-uniform 64-step greedy scan (bit-exact vs sequential greedy); then all
// 256 threads sweep later boxes against the chunk's kept set.
__global__ __launch_bounds__(256) void nms_kernel(
    const unsigned long long* __restrict__ keys,
    const float4* __restrict__ dec,
    int* __restrict__ keep)
{
    int c = blockIdx.x;
    __shared__ float sx1[NBOX], sy1[NBOX], sx2[NBOX], sy2[NBOX], sar[NBOX];
    __shared__ unsigned char ssup[NBOX];
    __shared__ unsigned char svalid[NBOX];
    __shared__ int sorig[NBOX];
    __shared__ unsigned long long s_keptmask;

    for (int i = threadIdx.x; i < NBOX; i += 256) {
        unsigned long long key = keys[c * NBOX + i];
        int idx = (NBOX - 1) - (int)(key & 0xFFFFFFFFull);
        int orig = c * NBOX + idx;
        float4 b = dec[orig];
        sx1[i] = b.x; sy1[i] = b.y; sx2[i] = b.z; sy2[i] = b.w;
        {
#pragma clang fp contract(off)
            sar[i] = (b.z - b.x) * (b.w - b.y);
        }
        ssup[i] = 0;
        svalid[i] = ((unsigned)(key >> 32)) != 0u;
        sorig[i] = orig;
        keep[orig] = 0;
    }
    __syncthreads();

    for (int base = 0; base < NBOX; base += 64) {
        if (threadIdx.x < 64) {
            int l = threadIdx.x;
            int me = base + l;
            float x1 = sx1[me], y1 = sy1[me], x2 = sx2[me], y2 = sy2[me], ar = sar[me];
            bool active = svalid[me] && !ssup[me];

            // row bit j: IoU(me, chunk[j]) > thresh, for j > l.
            // Uniform j-loop -> broadcast LDS reads (conflict-free).
            unsigned long long row = 0;
            for (int jj = 1; jj < 64; jj++) {
                int bj = base + jj;
                float iou = iou_f(x1, y1, x2, y2, ar,
                                  sx1[bj], sy1[bj], sx2[bj], sy2[bj], sar[bj]);
                if (jj > l && iou > NMS_THRESH) row |= 1ull << jj;
            }

            unsigned long long activemask = __ballot(active);
            unsigned long long sup = 0, keptmask = 0;
            for (int i = 0; i < 64; i++) {      // wave-uniform greedy scan
                unsigned long long row_i = __shfl(row, i);
                if (((activemask >> i) & 1ull) && !((sup >> i) & 1ull)) {
                    keptmask |= 1ull << i;
                    sup |= row_i;
                }
            }

            bool kept = (keptmask >> l) & 1ull;
            if (active && !kept) ssup[me] = 1;
            if (kept) keep[sorig[me]] = 1;
            if (l == 0) s_keptmask = keptmask;
        }
        __syncthreads();

        unsigned long long km0 = s_keptmask;
        if (km0) {
            for (int j = base + 64 + threadIdx.x; j < NBOX; j += 256) {
                if (ssup[j] || !svalid[j]) continue;
                float X1 = sx1[j], Y1 = sy1[j], X2 = sx2[j], Y2 = sy2[j], AR = sar[j];
                unsigned long long km = km0;
                while (km) {
                    int b = __builtin_ctzll(km);
                    km &= km - 1;
                    int bi = base + b;
                    float iou = iou_f(sx1[bi], sy1[bi], sx2[bi], sy2[bi], sar[bi],
                                      X1, Y1, X2, Y2, AR);
                    if (iou > NMS_THRESH) { ssup[j] = 1; break; }
                }
            }
        }
        __syncthreads();
    }
}

// ---------------- Kernel 4: count + exact radix-select of kth score ----------------
__global__ __launch_bounds__(1024) void select_kernel(
    const int* __restrict__ keep,
    const float* __restrict__ scores,
    int* __restrict__ stats)   // stats[0]=n_det, stats[1]=kth bits
{
    __shared__ int hist[256];
    __shared__ int s_count;
    __shared__ unsigned s_prefix;
    __shared__ int s_rank;
    int tid = threadIdx.x;

    if (tid == 0) s_count = 0;
    __syncthreads();

    int cnt = 0;
    for (int i = tid; i < NTOT; i += 1024) cnt += keep[i];
    atomicAdd(&s_count, cnt);
    __syncthreads();
    int n_det = s_count;

    if (tid == 0) { s_prefix = 0u; s_rank = DETS_PER_IMG; }
    __syncthreads();

    if (n_det > DETS_PER_IMG) {
        for (int pass = 3; pass >= 0; pass--) {
            int shift = pass * 8;
            if (tid < 256) hist[tid] = 0;
            __syncthreads();
            unsigned pref = s_prefix;
            unsigned pmask = (pass == 3) ? 0u : (0xFFFFFFFFu << ((pass + 1) * 8));
            for (int i = tid; i < NTOT; i += 1024) {
                if (keep[i]) {
                    unsigned b = __float_as_uint(scores[i]);  // positive -> bit-monotone
                    if ((b & pmask) == pref)
                        atomicAdd(&hist[(b >> shift) & 0xFF], 1);
                }
            }
            __syncthreads();
            if (tid == 0) {
                int r = s_rank;
                for (int bin = 255; bin >= 0; bin--) {
                    int cd = hist[bin];
                    if (r <= cd) {
                        s_prefix = pref | ((unsigned)bin << shift);
                        s_rank = r;
                        break;
                    }
                    r -= cd;
                }
            }
            __syncthreads();
        }
    }

    if (tid == 0) { stats[0] = n_det; stats[1] = (int)s_prefix; }
}

// ---------------- Kernel 5: final outputs ----------------
__global__ __launch_bounds__(256) void write_kernel(
    const float* __restrict__ scores,
    const float4* __restrict__ dec,
    const int* __restrict__ keep,
    const int* __restrict__ stats,
    const int* __restrict__ ulabels,
    float* __restrict__ out)
{
    int i = blockIdx.x * blockDim.x + threadIdx.x;
    if (i >= NTOT) return;

    int n_det = stats[0];
    float kth = __uint_as_float((unsigned)stats[1]);
    float s = scores[i];
    bool kf = keep[i] && (n_det <= DETS_PER_IMG || s >= kth);

    float4 b = dec[i];
    float* o5 = out + (size_t)i * 5;
    if (kf) {
        o5[0] = b.x; o5[1] = b.y; o5[2] = b.z; o5[3] = b.w; o5[4] = s;
    } else {
        o5[0] = 0.0f; o5[1] = 0.0f; o5[2] = 0.0f; o5[3] = 0.0f; o5[4] = 0.0f;
    }

    int c = i >> 11;
    out[NTOT * 5 + i] = (float)ulabels[c];
    out[NTOT * 5 + NTOT + i] = kf ? 1.0f : 0.0f;
}

extern "C" void kernel_launch(void* const* d_in, const int* in_sizes, int n_in,
                              void* d_out, int out_size, void* d_ws, size_t ws_size,
                              hipStream_t stream) {
    (void)in_sizes; (void)n_in; (void)out_size; (void)ws_size;

    const float* class_logit    = (const float*)d_in[0];   // (NTOT,2)
    const float* box_regression = (const float*)d_in[1];   // (NTOT,8)
    const float* proposal_boxes = (const float*)d_in[2];   // (NBOX,4)
    const int*   unique_labels  = (const int*)d_in[3];     // (NCLS)

    char* ws = (char*)d_ws;
    float* scores            = (float*)ws;                                  // 131072 B
    float4* dec              = (float4*)(ws + 131072);                      // 524288 B
    unsigned long long* keys = (unsigned long long*)(ws + 131072 + 524288); // 262144 B
    int* keep                = (int*)(ws + 917504);                         // 131072 B
    int* stats               = (int*)(ws + 1048576);                        // 8 B

    float* out = (float*)d_out;

    decode_kernel<<<NTOT / 256, 256, 0, stream>>>(class_logit, box_regression,
                                                  proposal_boxes, scores, dec);
    sort_kernel<<<NCLS, 256, 0, stream>>>(scores, keys);
    nms_kernel<<<NCLS, 256, 0, stream>>>(keys, dec, keep);
    select_kernel<<<1, 1024, 0, stream>>>(keep, scores, stats);
    write_kernel<<<NTOT / 256, 256, 0, stream>>>(scores, dec, keep, stats,
                                                 unique_labels, out);
}

// Round 3
// 770.862 us; speedup vs baseline: 2.5010x; 1.9785x over previous
//
#include <hip/hip_runtime.h>
#include <hip/hip_bf16.h>

#define NCLS 16
#define NBOX 2048
#define NTOT (NCLS * NBOX)
#define NCHUNK 32                 /* NBOX / 64 */
#define SCORE_THRESH 0.05f
#define NMS_THRESH 0.5f
#define DETS_PER_IMG 100
#define BBOX_CLIP 4.135166556742356f  /* log(1000/16) */

typedef unsigned long long u64;

// IoU identical (op order) to the reference; symmetric in the two boxes.
__device__ __forceinline__ float iou_f(float x1, float y1, float x2, float y2, float ar,
                                       float X1, float Y1, float X2, float Y2, float AR) {
#pragma clang fp contract(off)
    float lx = fmaxf(x1, X1);
    float ly = fmaxf(y1, Y1);
    float rx = fminf(x2, X2);
    float ry = fminf(y2, Y2);
    float w = fmaxf(rx - lx, 0.0f);
    float h = fmaxf(ry - ly, 0.0f);
    float inter = w * h;
    return inter / (ar + AR - inter + 1e-12f);
}

// ---------------- Kernel 1: fused decode + per-class bitonic sort ----------------
// key = (monotone_score_bits << 32) | (2047 - idx); invalid -> score part 0.
// Descending sort => stable emulation of jnp.argsort(-masked).
// Optionally emits sorted SoA (boxes, areas, orig index) + packed validity words.
__global__ __launch_bounds__(256) void sortdecode_kernel(
    const float* __restrict__ logits,   // (NTOT, 2)
    const float* __restrict__ regr,     // (NTOT, 8)
    const float* __restrict__ props,    // (NBOX, 4)
    float* __restrict__ scores,         // (NTOT)
    float4* __restrict__ dec,           // (NTOT)
    u64* __restrict__ keys_out,         // (NTOT)
    float4* __restrict__ sbox4,         // (NTOT) sorted boxes (fast path)
    float* __restrict__ sarea,          // (NTOT) sorted areas
    int* __restrict__ sorig,            // (NTOT) sorted -> original index
    u64* __restrict__ svalidw,          // (NCLS*NCHUNK) packed validity
    int write_soa)
{
    int c = blockIdx.x;
    __shared__ u64 sk[NBOX];

    // ---- decode + key init ----
    for (int t = threadIdx.x; t < NBOX; t += 256) {
#pragma clang fp contract(off)
        int i = c * NBOX + t;
        float x0 = logits[2 * i + 0];
        float x1 = logits[2 * i + 1];
        float m = fmaxf(x0, x1);
        float e0 = expf(x0 - m);
        float e1 = expf(x1 - m);
        float score = e1 / (e0 + e1);
        scores[i] = score;

        float px1 = props[4 * t + 0];
        float py1 = props[4 * t + 1];
        float px2 = props[4 * t + 2];
        float py2 = props[4 * t + 3];

        float w  = px2 - px1 + 1.0f;
        float h  = py2 - py1 + 1.0f;
        float cx = px1 + 0.5f * w;
        float cy = py1 + 0.5f * h;

        float dx = regr[8 * i + 4] / 10.0f;
        float dy = regr[8 * i + 5] / 10.0f;
        float dw = fminf(regr[8 * i + 6] / 5.0f, BBOX_CLIP);
        float dh = fminf(regr[8 * i + 7] / 5.0f, BBOX_CLIP);

        float pcx = dx * w + cx;
        float pcy = dy * h + cy;
        float pw  = expf(dw) * w;
        float ph  = expf(dh) * h;

        float b0 = pcx - 0.5f * pw;
        float b1 = pcy - 0.5f * ph;
        float b2 = pcx + 0.5f * pw - 1.0f;
        float b3 = pcy + 0.5f * ph - 1.0f;

        b0 = fminf(fmaxf(b0, 0.0f), 1332.0f);
        b1 = fminf(fmaxf(b1, 0.0f), 799.0f);
        b2 = fminf(fmaxf(b2, 0.0f), 1332.0f);
        b3 = fminf(fmaxf(b3, 0.0f), 799.0f);

        dec[i] = make_float4(b0, b1, b2, b3);

        unsigned mono = 0u;
        if (score > SCORE_THRESH) mono = __float_as_uint(score) | 0x80000000u;
        sk[t] = ((u64)mono << 32) | (u64)(unsigned)(NBOX - 1 - t);
    }
    __syncthreads();

    // ---- bitonic sort (descending) ----
    for (int k = 2; k <= NBOX; k <<= 1) {
        for (int j = k >> 1; j > 0; j >>= 1) {
            for (int i = threadIdx.x; i < NBOX; i += 256) {
                int ixj = i ^ j;
                if (ixj > i) {
                    u64 a = sk[i];
                    u64 b = sk[ixj];
                    bool desc = ((i & k) == 0);
                    bool sw = desc ? (a < b) : (a > b);
                    if (sw) { sk[i] = b; sk[ixj] = a; }
                }
            }
            __syncthreads();
        }
    }

    for (int t = threadIdx.x; t < NBOX; t += 256)
        keys_out[c * NBOX + t] = sk[t];

    if (write_soa) {
        for (int t = threadIdx.x; t < NBOX; t += 256) {
            u64 key = sk[t];
            int idx = (NBOX - 1) - (int)(key & 0xFFFFFFFFull);
            int orig = c * NBOX + idx;
            float4 b = dec[orig];   // written before first barrier -> visible in-block
            sbox4[c * NBOX + t] = b;
            {
#pragma clang fp contract(off)
                sarea[c * NBOX + t] = (b.z - b.x) * (b.w - b.y);
            }
            sorig[c * NBOX + t] = orig;
        }
        for (int g = 0; g < 8; g++) {
            int t = g * 256 + threadIdx.x;
            bool v = ((unsigned)(sk[t] >> 32)) != 0u;
            u64 bal = __ballot(v);
            if ((threadIdx.x & 63) == 0)
                svalidw[c * NCHUNK + g * 4 + (threadIdx.x >> 6)] = bal;
        }
    }
}

// ---------------- Kernel 2 (fast): IoU bitmask ----------------
// block = (class c, row-chunk I); computes mask rows for 64 rows vs all 2048
// cols; bit set iff col > row && IoU > thresh. 32 u64 words per row.
__global__ __launch_bounds__(256) void mask_kernel(
    const float4* __restrict__ sbox4,
    const float* __restrict__ sarea,
    u64* __restrict__ mask)
{
    int c = blockIdx.x >> 5;
    int I = blockIdx.x & 31;
    __shared__ float4 box[NBOX];   // 32 KB
    __shared__ float  area[NBOX];  // 8 KB

    for (int i = threadIdx.x; i < NBOX; i += 256) {
        box[i]  = sbox4[c * NBOX + i];
        area[i] = sarea[c * NBOX + i];
    }
    __syncthreads();

    int r = threadIdx.x & 63;
    int g = threadIdx.x >> 6;
    int row = I * 64 + r;
    float4 rb = box[row];
    float rar = area[row];
    u64* mrow = mask + ((size_t)c * NBOX + row) * NCHUNK;

    for (int J = g; J < NCHUNK; J += 4) {
        u64 w = 0;
        if (J >= I) {
            int cbase = J * 64;
            for (int j2 = 0; j2 < 64; j2++) {
                int col = cbase + j2;
                float4 cb = box[col];          // wave-uniform -> LDS broadcast
                float iou = iou_f(rb.x, rb.y, rb.z, rb.w, rar,
                                  cb.x, cb.y, cb.z, cb.w, area[col]);
                if (col > row && iou > NMS_THRESH) w |= 1ull << j2;
            }
        }
        mrow[J] = w;
    }
}

// ---------------- Kernel 3 (fast): greedy resolve on precomputed bits ----------------
// One wave per class. Lane l<32 owns suppression word for chunk l.
__global__ __launch_bounds__(64) void resolve_kernel(
    const u64* __restrict__ mask,
    const u64* __restrict__ svalidw,
    const int* __restrict__ sorig,
    int* __restrict__ keep)
{
    int c = blockIdx.x;
    int lane = threadIdx.x;
    const u64* M = mask + (size_t)c * NBOX * NCHUNK;
    u64 sup = 0;
    u64 validw = (lane < NCHUNK) ? svalidw[c * NCHUNK + lane] : 0ull;

    for (int I = 0; I < NCHUNK; I++) {
        // diag word of this chunk: lane i -> row (I*64+i), word I
        u64 diagw = M[(size_t)(I * 64 + lane) * NCHUNK + I];
        u64 supI = __shfl(sup, I);
        u64 vI   = __shfl(validw, I);

        u64 sup_acc = supI;
        u64 kept = 0;
        u64 rem = vI & ~sup_acc;
        while (rem) {                         // iterations == kept count
            int i = __builtin_ctzll(rem);
            kept |= 1ull << i;
            u64 row = __shfl(diagw, i);       // only bits > i set
            sup_acc |= row;
            rem &= ~sup_acc;
            rem &= ~(1ull << i);
        }

        keep[sorig[c * NBOX + I * 64 + lane]] = (int)((kept >> lane) & 1ull);

        // OR kept rows' future words into distributed sup
        u64 k2 = kept;
        while (k2) {
            int i = __builtin_ctzll(k2);
            k2 &= k2 - 1;
            u64 w = M[(size_t)(I * 64 + i) * NCHUNK + (lane & 31)];  // coalesced
            if (lane < NCHUNK) sup |= w;      // words J<I are zero -> harmless
        }
    }
}

// ---------------- Kernel 3 (fallback): per-class blocked greedy NMS ----------------
__global__ __launch_bounds__(256) void nms_kernel(
    const u64* __restrict__ keys,
    const float4* __restrict__ dec,
    int* __restrict__ keep)
{
    int c = blockIdx.x;
    __shared__ float sx1[NBOX], sy1[NBOX], sx2[NBOX], sy2[NBOX], sar[NBOX];
    __shared__ unsigned char ssup[NBOX];
    __shared__ unsigned char svalid[NBOX];
    __shared__ int sorig_l[NBOX];
    __shared__ u64 s_keptmask;

    for (int i = threadIdx.x; i < NBOX; i += 256) {
        u64 key = keys[c * NBOX + i];
        int idx = (NBOX - 1) - (int)(key & 0xFFFFFFFFull);
        int orig = c * NBOX + idx;
        float4 b = dec[orig];
        sx1[i] = b.x; sy1[i] = b.y; sx2[i] = b.z; sy2[i] = b.w;
        {
#pragma clang fp contract(off)
            sar[i] = (b.z - b.x) * (b.w - b.y);
        }
        ssup[i] = 0;
        svalid[i] = ((unsigned)(key >> 32)) != 0u;
        sorig_l[i] = orig;
        keep[orig] = 0;
    }
    __syncthreads();

    for (int base = 0; base < NBOX; base += 64) {
        if (threadIdx.x < 64) {
            int l = threadIdx.x;
            int me = base + l;
            float x1 = sx1[me], y1 = sy1[me], x2 = sx2[me], y2 = sy2[me], ar = sar[me];
            bool active = svalid[me] && !ssup[me];

            u64 row = 0;
            for (int jj = 1; jj < 64; jj++) {
                int bj = base + jj;
                float iou = iou_f(x1, y1, x2, y2, ar,
                                  sx1[bj], sy1[bj], sx2[bj], sy2[bj], sar[bj]);
                if (jj > l && iou > NMS_THRESH) row |= 1ull << jj;
            }

            u64 activemask = __ballot(active);
            u64 sup = 0, keptmask = 0;
            for (int i = 0; i < 64; i++) {
                u64 row_i = __shfl(row, i);
                if (((activemask >> i) & 1ull) && !((sup >> i) & 1ull)) {
                    keptmask |= 1ull << i;
                    sup |= row_i;
                }
            }

            bool kept = (keptmask >> l) & 1ull;
            if (active && !kept) ssup[me] = 1;
            if (kept) keep[sorig_l[me]] = 1;
            if (l == 0) s_keptmask = keptmask;
        }
        __syncthreads();

        u64 km0 = s_keptmask;
        if (km0) {
            for (int j = base + 64 + threadIdx.x; j < NBOX; j += 256) {
                if (ssup[j] || !svalid[j]) continue;
                float X1 = sx1[j], Y1 = sy1[j], X2 = sx2[j], Y2 = sy2[j], AR = sar[j];
                u64 km = km0;
                while (km) {
                    int b = __builtin_ctzll(km);
                    km &= km - 1;
                    int bi = base + b;
                    float iou = iou_f(sx1[bi], sy1[bi], sx2[bi], sy2[bi], sar[bi],
                                      X1, Y1, X2, Y2, AR);
                    if (iou > NMS_THRESH) { ssup[j] = 1; break; }
                }
            }
        }
        __syncthreads();
    }
}

// ---------------- Kernel 4: count + exact radix-select of kth score ----------------
__global__ __launch_bounds__(1024) void select_kernel(
    const int* __restrict__ keep,
    const float* __restrict__ scores,
    int* __restrict__ stats)   // stats[0]=n_det, stats[1]=kth bits
{
    __shared__ int hist[256];
    __shared__ int s_count;
    __shared__ unsigned s_prefix;
    __shared__ int s_rank;
    int tid = threadIdx.x;

    if (tid == 0) s_count = 0;
    __syncthreads();

    int cnt = 0;
    for (int i = tid; i < NTOT; i += 1024) cnt += keep[i];
    atomicAdd(&s_count, cnt);
    __syncthreads();
    int n_det = s_count;

    if (tid == 0) { s_prefix = 0u; s_rank = DETS_PER_IMG; }
    __syncthreads();

    if (n_det > DETS_PER_IMG) {
        for (int pass = 3; pass >= 0; pass--) {
            int shift = pass * 8;
            if (tid < 256) hist[tid] = 0;
            __syncthreads();
            unsigned pref = s_prefix;
            unsigned pmask = (pass == 3) ? 0u : (0xFFFFFFFFu << ((pass + 1) * 8));
            for (int i = tid; i < NTOT; i += 1024) {
                if (keep[i]) {
                    unsigned b = __float_as_uint(scores[i]);
                    if ((b & pmask) == pref)
                        atomicAdd(&hist[(b >> shift) & 0xFF], 1);
                }
            }
            __syncthreads();
            if (tid == 0) {
                int r = s_rank;
                for (int bin = 255; bin >= 0; bin--) {
                    int cd = hist[bin];
                    if (r <= cd) {
                        s_prefix = pref | ((unsigned)bin << shift);
                        s_rank = r;
                        break;
                    }
                    r -= cd;
                }
            }
            __syncthreads();
        }
    }

    if (tid == 0) { stats[0] = n_det; stats[1] = (int)s_prefix; }
}

// ---------------- Kernel 5: final outputs ----------------
__global__ __launch_bounds__(256) void write_kernel(
    const float* __restrict__ scores,
    const float4* __restrict__ dec,
    const int* __restrict__ keep,
    const int* __restrict__ stats,
    const int* __restrict__ ulabels,
    float* __restrict__ out)
{
    int i = blockIdx.x * blockDim.x + threadIdx.x;
    if (i >= NTOT) return;

    int n_det = stats[0];
    float kth = __uint_as_float((unsigned)stats[1]);
    float s = scores[i];
    bool kf = keep[i] && (n_det <= DETS_PER_IMG || s >= kth);

    float4 b = dec[i];
    float* o5 = out + (size_t)i * 5;
    if (kf) {
        o5[0] = b.x; o5[1] = b.y; o5[2] = b.z; o5[3] = b.w; o5[4] = s;
    } else {
        o5[0] = 0.0f; o5[1] = 0.0f; o5[2] = 0.0f; o5[3] = 0.0f; o5[4] = 0.0f;
    }

    int c = i >> 11;
    out[NTOT * 5 + i] = (float)ulabels[c];
    out[NTOT * 5 + NTOT + i] = kf ? 1.0f : 0.0f;
}

extern "C" void kernel_launch(void* const* d_in, const int* in_sizes, int n_in,
                              void* d_out, int out_size, void* d_ws, size_t ws_size,
                              hipStream_t stream) {
    (void)in_sizes; (void)n_in; (void)out_size;

    const float* class_logit    = (const float*)d_in[0];   // (NTOT,2)
    const float* box_regression = (const float*)d_in[1];   // (NTOT,8)
    const float* proposal_boxes = (const float*)d_in[2];   // (NBOX,4)
    const int*   unique_labels  = (const int*)d_in[3];     // (NCLS)

    char* ws = (char*)d_ws;
    // Common layout (fits in the proven-available 1.05 MB):
    float* scores = (float*)(ws + 0);              // 131072
    float4* dec   = (float4*)(ws + 131072);        // 524288
    u64* keys     = (u64*)(ws + 655360);           // 262144
    int* keep     = (int*)(ws + 917504);           // 131072
    int* stats    = (int*)(ws + 1048576);          // 8
    // Fast-path extras:
    float4* sbox4 = (float4*)(ws + 1048832);       // 524288
    float* sarea  = (float*)(ws + 1573120);        // 131072
    int* sorig    = (int*)(ws + 1704192);          // 131072
    u64* svalidw  = (u64*)(ws + 1835264);          // 4096
    u64* mask     = (u64*)(ws + 1839360);          // 8388608
    const size_t FAST_NEED = 1839360 + (size_t)NCLS * NBOX * NCHUNK * 8;

    float* out = (float*)d_out;
    bool fast = (ws_size >= FAST_NEED);

    sortdecode_kernel<<<NCLS, 256, 0, stream>>>(class_logit, box_regression,
                                                proposal_boxes, scores, dec, keys,
                                                sbox4, sarea, sorig, svalidw,
                                                fast ? 1 : 0);
    if (fast) {
        mask_kernel<<<NCLS * NCHUNK, 256, 0, stream>>>(sbox4, sarea, mask);
        resolve_kernel<<<NCLS, 64, 0, stream>>>(mask, svalidw, sorig, keep);
    } else {
        nms_kernel<<<NCLS, 256, 0, stream>>>(keys, dec, keep);
    }
    select_kernel<<<1, 1024, 0, stream>>>(keep, scores, stats);
    write_kernel<<<NTOT / 256, 256, 0, stream>>>(scores, dec, keep, stats,
                                                 unique_labels, out);
}

// Round 4
// 405.867 us; speedup vs baseline: 4.7501x; 1.8993x over previous
//
#include <hip/hip_runtime.h>
#include <hip/hip_bf16.h>

#define NCLS 16
#define NBOX 2048
#define NTOT (NCLS * NBOX)
#define NCHUNK 32                 /* NBOX / 64 */
#define SCORE_THRESH 0.05f
#define NMS_THRESH 0.5f
#define DETS_PER_IMG 100
#define BBOX_CLIP 4.135166556742356f  /* log(1000/16) */

typedef unsigned long long u64;

// IoU identical (op order) to the reference; symmetric in the two boxes.
__device__ __forceinline__ float iou_f(float x1, float y1, float x2, float y2, float ar,
                                       float X1, float Y1, float X2, float Y2, float AR) {
#pragma clang fp contract(off)
    float lx = fmaxf(x1, X1);
    float ly = fmaxf(y1, Y1);
    float rx = fminf(x2, X2);
    float ry = fminf(y2, Y2);
    float w = fmaxf(rx - lx, 0.0f);
    float h = fmaxf(ry - ly, 0.0f);
    float inter = w * h;
    return inter / (ar + AR - inter + 1e-12f);
}

// ---------------- Kernel 1: fused decode + per-class bitonic sort ----------------
// key = (monotone_score_bits << 32) | (2047 - idx); invalid -> score part 0.
// Descending sort => stable emulation of jnp.argsort(-masked).
// Emits dec (orig order), keys (sorted), sorted SoA boxes/areas.
__global__ __launch_bounds__(256) void sortdecode_kernel(
    const float* __restrict__ logits,   // (NTOT, 2)
    const float* __restrict__ regr,     // (NTOT, 8)
    const float* __restrict__ props,    // (NBOX, 4)
    float4* __restrict__ dec,           // (NTOT)
    u64* __restrict__ keys_out,         // (NTOT)
    float4* __restrict__ sbox4,         // (NTOT) sorted boxes
    float* __restrict__ sarea)          // (NTOT) sorted areas
{
    int c = blockIdx.x;
    __shared__ u64 sk[NBOX];

    // ---- decode + key init ----
    for (int t = threadIdx.x; t < NBOX; t += 256) {
#pragma clang fp contract(off)
        int i = c * NBOX + t;
        float x0 = logits[2 * i + 0];
        float x1 = logits[2 * i + 1];
        float m = fmaxf(x0, x1);
        float e0 = expf(x0 - m);
        float e1 = expf(x1 - m);
        float score = e1 / (e0 + e1);

        float px1 = props[4 * t + 0];
        float py1 = props[4 * t + 1];
        float px2 = props[4 * t + 2];
        float py2 = props[4 * t + 3];

        float w  = px2 - px1 + 1.0f;
        float h  = py2 - py1 + 1.0f;
        float cx = px1 + 0.5f * w;
        float cy = py1 + 0.5f * h;

        float dx = regr[8 * i + 4] / 10.0f;
        float dy = regr[8 * i + 5] / 10.0f;
        float dw = fminf(regr[8 * i + 6] / 5.0f, BBOX_CLIP);
        float dh = fminf(regr[8 * i + 7] / 5.0f, BBOX_CLIP);

        float pcx = dx * w + cx;
        float pcy = dy * h + cy;
        float pw  = expf(dw) * w;
        float ph  = expf(dh) * h;

        float b0 = pcx - 0.5f * pw;
        float b1 = pcy - 0.5f * ph;
        float b2 = pcx + 0.5f * pw - 1.0f;
        float b3 = pcy + 0.5f * ph - 1.0f;

        b0 = fminf(fmaxf(b0, 0.0f), 1332.0f);
        b1 = fminf(fmaxf(b1, 0.0f), 799.0f);
        b2 = fminf(fmaxf(b2, 0.0f), 1332.0f);
        b3 = fminf(fmaxf(b3, 0.0f), 799.0f);

        dec[i] = make_float4(b0, b1, b2, b3);

        unsigned mono = 0u;
        if (score > SCORE_THRESH) mono = __float_as_uint(score) | 0x80000000u;
        sk[t] = ((u64)mono << 32) | (u64)(unsigned)(NBOX - 1 - t);
    }
    __syncthreads();

    // ---- bitonic sort (descending) ----
    for (int k = 2; k <= NBOX; k <<= 1) {
        for (int j = k >> 1; j > 0; j >>= 1) {
            for (int i = threadIdx.x; i < NBOX; i += 256) {
                int ixj = i ^ j;
                if (ixj > i) {
                    u64 a = sk[i];
                    u64 b = sk[ixj];
                    bool desc = ((i & k) == 0);
                    bool sw = desc ? (a < b) : (a > b);
                    if (sw) { sk[i] = b; sk[ixj] = a; }
                }
            }
            __syncthreads();
        }
    }

    for (int t = threadIdx.x; t < NBOX; t += 256) {
        u64 key = sk[t];
        keys_out[c * NBOX + t] = key;
        int idx = (NBOX - 1) - (int)(key & 0xFFFFFFFFull);
        int orig = c * NBOX + idx;
        float4 b = dec[orig];   // same block wrote dec before the barrier
        sbox4[c * NBOX + t] = b;
        {
#pragma clang fp contract(off)
            sarea[c * NBOX + t] = (b.z - b.x) * (b.w - b.y);
        }
    }
}

// ---------------- Kernel 2: IoU bitmask (balanced upper-tri) ----------------
// block = (class c, pair p) handles row-chunks I=p and I=31-p -> 33 chunk-cols
// of work per block. Also emits compact diag words for the resolve scan.
__global__ __launch_bounds__(256) void mask_kernel(
    const float4* __restrict__ sbox4,
    const float* __restrict__ sarea,
    u64* __restrict__ mask,
    u64* __restrict__ diag)
{
    int c = blockIdx.x >> 4;
    int p = blockIdx.x & 15;
    __shared__ float4 box[NBOX];   // 32 KB
    __shared__ float  area[NBOX];  // 8 KB

    for (int i = threadIdx.x; i < NBOX; i += 256) {
        box[i]  = sbox4[c * NBOX + i];
        area[i] = sarea[c * NBOX + i];
    }
    __syncthreads();

    int r = threadIdx.x & 63;
    int g = threadIdx.x >> 6;

    for (int pass = 0; pass < 2; pass++) {
        int I = pass ? (31 - p) : p;
        int row = I * 64 + r;
        float4 rb = box[row];
        float rar = area[row];
        u64* mrow = mask + ((size_t)c * NBOX + row) * NCHUNK;

        for (int J = g; J < NCHUNK; J += 4) {
            u64 w = 0;
            if (J >= I) {
                int cbase = J * 64;
#pragma unroll 8
                for (int j2 = 0; j2 < 64; j2++) {
                    int col = cbase + j2;
                    float4 cb = box[col];          // wave-uniform -> LDS broadcast
                    float iou = iou_f(rb.x, rb.y, rb.z, rb.w, rar,
                                      cb.x, cb.y, cb.z, cb.w, area[col]);
                    if (col > row && iou > NMS_THRESH) w |= 1ull << j2;
                }
            }
            mrow[J] = w;
            if (J == I) diag[((size_t)c * NCHUNK + I) * 64 + r] = w;
        }
    }
}

// ---------------- Kernel 3: greedy resolve on precomputed bits ----------------
// 256 threads per class. Wave 0 does a scalar 64-step greedy scan per chunk;
// then all 4 waves OR kept rows' mask words into a 32-word LDS suppression
// vector (8 rows x 32 words in flight, coalesced 256B row loads).
__global__ __launch_bounds__(256) void resolve_kernel(
    const u64* __restrict__ keys,
    const u64* __restrict__ mask,
    const u64* __restrict__ diag,
    unsigned* __restrict__ keepbits)
{
    int c = blockIdx.x;
    int tid = threadIdx.x;
    __shared__ u64 lds_sup[NCHUNK];
    __shared__ u64 lds_kept;
    const u64* M = mask + (size_t)c * NBOX * NCHUNK;

    if (tid < NCHUNK) lds_sup[tid] = 0ull;
    __syncthreads();

    for (int I = 0; I < NCHUNK; I++) {
        if (tid < 64) {
            u64 key = keys[c * NBOX + I * 64 + tid];
            unsigned mono = (unsigned)(key >> 32);
            u64 vI = __ballot(mono != 0u);             // SGPR, wave-uniform
            u64 dw = diag[((size_t)c * NCHUNK + I) * 64 + tid];
            u64 avail = vI & ~lds_sup[I];
            u64 kept = 0;
#pragma unroll
            for (int i = 0; i < 64; i++) {             // scalar greedy scan
                u64 m = 1ull << i;
                u64 row_i = __shfl(dw, i);             // literal lane -> readlane
                if (avail & m) { kept |= m; avail &= ~row_i; }
            }
            int orig = c * NBOX + (NBOX - 1) - (int)(key & 0xFFFFFFFFull);
            keepbits[orig] = ((kept >> tid) & 1ull) ? (mono & 0x7FFFFFFFu) : 0u;
            if (tid == 0) lds_kept = kept;
        }
        __syncthreads();

        u64 kept = lds_kept;
        int r0 = tid >> 5;
        int j  = tid & 31;
#pragma unroll
        for (int r = r0; r < 64; r += 8) {
            if ((kept >> r) & 1ull) {
                u64 w = M[(size_t)(I * 64 + r) * NCHUNK + j];  // coalesced
                if (w) atomicOr(&lds_sup[j], w);
            }
        }
        __syncthreads();
    }
}

// ---------------- Kernel 4: count + exact radix-select of kth score ----------------
__global__ __launch_bounds__(1024) void select_kernel(
    const unsigned* __restrict__ keepbits,
    int* __restrict__ stats)   // stats[0]=n_det, stats[1]=kth bits
{
    __shared__ int hist[256];
    __shared__ int s_count;
    __shared__ unsigned s_prefix;
    __shared__ int s_rank;
    int tid = threadIdx.x;
    const uint4* kb4 = (const uint4*)keepbits;

    if (tid == 0) s_count = 0;
    __syncthreads();

    int cnt = 0;
    for (int i = tid; i < NTOT / 4; i += 1024) {
        uint4 v = kb4[i];
        cnt += (v.x != 0) + (v.y != 0) + (v.z != 0) + (v.w != 0);
    }
    atomicAdd(&s_count, cnt);
    __syncthreads();
    int n_det = s_count;

    if (tid == 0) { s_prefix = 0u; s_rank = DETS_PER_IMG; }
    __syncthreads();

    if (n_det > DETS_PER_IMG) {
        for (int pass = 3; pass >= 0; pass--) {
            int shift = pass * 8;
            if (tid < 256) hist[tid] = 0;
            __syncthreads();
            unsigned pref = s_prefix;
            unsigned pmask = (pass == 3) ? 0u : (0xFFFFFFFFu << ((pass + 1) * 8));
            for (int i = tid; i < NTOT / 4; i += 1024) {
                uint4 v = kb4[i];
                unsigned b;
                b = v.x; if (b && (b & pmask) == pref) atomicAdd(&hist[(b >> shift) & 0xFF], 1);
                b = v.y; if (b && (b & pmask) == pref) atomicAdd(&hist[(b >> shift) & 0xFF], 1);
                b = v.z; if (b && (b & pmask) == pref) atomicAdd(&hist[(b >> shift) & 0xFF], 1);
                b = v.w; if (b && (b & pmask) == pref) atomicAdd(&hist[(b >> shift) & 0xFF], 1);
            }
            __syncthreads();
            if (tid == 0) {
                int r = s_rank;
                for (int bin = 255; bin >= 0; bin--) {
                    int cd = hist[bin];
                    if (r <= cd) {
                        s_prefix = pref | ((unsigned)bin << shift);
                        s_rank = r;
                        break;
                    }
                    r -= cd;
                }
            }
            __syncthreads();
        }
    }

    if (tid == 0) { stats[0] = n_det; stats[1] = (int)s_prefix; }
}

// ---------------- Kernel 5: final outputs ----------------
__global__ __launch_bounds__(256) void write_kernel(
    const unsigned* __restrict__ keepbits,
    const float4* __restrict__ dec,
    const int* __restrict__ stats,
    const int* __restrict__ ulabels,
    float* __restrict__ out)
{
    int i = blockIdx.x * blockDim.x + threadIdx.x;
    if (i >= NTOT) return;

    int n_det = stats[0];
    unsigned kth = (unsigned)stats[1];
    unsigned kb = keepbits[i];
    bool kf = kb && (n_det <= DETS_PER_IMG || kb >= kth);  // uint cmp == float cmp (positive)

    float4 b = dec[i];
    float* o5 = out + (size_t)i * 5;
    if (kf) {
        o5[0] = b.x; o5[1] = b.y; o5[2] = b.z; o5[3] = b.w;
        o5[4] = __uint_as_float(kb);
    } else {
        o5[0] = 0.0f; o5[1] = 0.0f; o5[2] = 0.0f; o5[3] = 0.0f; o5[4] = 0.0f;
    }

    int c = i >> 11;
    out[NTOT * 5 + i] = (float)ulabels[c];
    out[NTOT * 5 + NTOT + i] = kf ? 1.0f : 0.0f;
}

extern "C" void kernel_launch(void* const* d_in, const int* in_sizes, int n_in,
                              void* d_out, int out_size, void* d_ws, size_t ws_size,
                              hipStream_t stream) {
    (void)in_sizes; (void)n_in; (void)out_size; (void)ws_size;

    const float* class_logit    = (const float*)d_in[0];   // (NTOT,2)
    const float* box_regression = (const float*)d_in[1];   // (NTOT,8)
    const float* proposal_boxes = (const float*)d_in[2];   // (NBOX,4)
    const int*   unique_labels  = (const int*)d_in[3];     // (NCLS)

    char* ws = (char*)d_ws;
    float4* dec        = (float4*)(ws + 0);         // 524288
    u64* keys          = (u64*)(ws + 524288);       // 262144
    float4* sbox4      = (float4*)(ws + 786432);    // 524288
    float* sarea       = (float*)(ws + 1310720);    // 131072
    unsigned* keepbits = (unsigned*)(ws + 1441792); // 131072
    u64* diag          = (u64*)(ws + 1572864);      // 262144
    int* stats         = (int*)(ws + 1835008);      // 256
    u64* mask          = (u64*)(ws + 1835264);      // 8388608  (total ~9.75 MB; round-3 confirmed available)

    float* out = (float*)d_out;

    sortdecode_kernel<<<NCLS, 256, 0, stream>>>(class_logit, box_regression,
                                                proposal_boxes, dec, keys,
                                                sbox4, sarea);
    mask_kernel<<<NCLS * 16, 256, 0, stream>>>(sbox4, sarea, mask, diag);
    resolve_kernel<<<NCLS, 256, 0, stream>>>(keys, mask, diag, keepbits);
    select_kernel<<<1, 1024, 0, stream>>>(keepbits, stats);
    write_kernel<<<NTOT / 256, 256, 0, stream>>>(keepbits, dec, stats,
                                                 unique_labels, out);
}

// Round 5
// 304.176 us; speedup vs baseline: 6.3381x; 1.3343x over previous
//
#include <hip/hip_runtime.h>
#include <hip/hip_bf16.h>

#define NCLS 16
#define NBOX 2048
#define NTOT (NCLS * NBOX)
#define NCHUNK 32                 /* NBOX / 64 */
#define SCORE_THRESH 0.05f
#define NMS_THRESH 0.5f
#define DETS_PER_IMG 100
#define BBOX_CLIP 4.135166556742356f  /* log(1000/16) */

typedef unsigned long long u64;

// IoU identical (op order) to the reference; symmetric in the two boxes.
__device__ __forceinline__ float iou_f(float x1, float y1, float x2, float y2, float ar,
                                       float X1, float Y1, float X2, float Y2, float AR) {
#pragma clang fp contract(off)
    float lx = fmaxf(x1, X1);
    float ly = fmaxf(y1, Y1);
    float rx = fminf(x2, X2);
    float ry = fminf(y2, Y2);
    float w = fmaxf(rx - lx, 0.0f);
    float h = fmaxf(ry - ly, 0.0f);
    float inter = w * h;
    return inter / (ar + AR - inter + 1e-12f);
}

// ---------------- Kernel 1: fused decode + per-class bitonic sort ----------------
__global__ __launch_bounds__(256) void sortdecode_kernel(
    const float* __restrict__ logits,   // (NTOT, 2)
    const float* __restrict__ regr,     // (NTOT, 8)
    const float* __restrict__ props,    // (NBOX, 4)
    float4* __restrict__ dec,           // (NTOT)
    u64* __restrict__ keys_out,         // (NTOT)
    float4* __restrict__ sbox4,         // (NTOT) sorted boxes
    float* __restrict__ sarea)          // (NTOT) sorted areas
{
    int c = blockIdx.x;
    __shared__ u64 sk[NBOX];

    for (int t = threadIdx.x; t < NBOX; t += 256) {
#pragma clang fp contract(off)
        int i = c * NBOX + t;
        float x0 = logits[2 * i + 0];
        float x1 = logits[2 * i + 1];
        float m = fmaxf(x0, x1);
        float e0 = expf(x0 - m);
        float e1 = expf(x1 - m);
        float score = e1 / (e0 + e1);

        float px1 = props[4 * t + 0];
        float py1 = props[4 * t + 1];
        float px2 = props[4 * t + 2];
        float py2 = props[4 * t + 3];

        float w  = px2 - px1 + 1.0f;
        float h  = py2 - py1 + 1.0f;
        float cx = px1 + 0.5f * w;
        float cy = py1 + 0.5f * h;

        float dx = regr[8 * i + 4] / 10.0f;
        float dy = regr[8 * i + 5] / 10.0f;
        float dw = fminf(regr[8 * i + 6] / 5.0f, BBOX_CLIP);
        float dh = fminf(regr[8 * i + 7] / 5.0f, BBOX_CLIP);

        float pcx = dx * w + cx;
        float pcy = dy * h + cy;
        float pw  = expf(dw) * w;
        float ph  = expf(dh) * h;

        float b0 = pcx - 0.5f * pw;
        float b1 = pcy - 0.5f * ph;
        float b2 = pcx + 0.5f * pw - 1.0f;
        float b3 = pcy + 0.5f * ph - 1.0f;

        b0 = fminf(fmaxf(b0, 0.0f), 1332.0f);
        b1 = fminf(fmaxf(b1, 0.0f), 799.0f);
        b2 = fminf(fmaxf(b2, 0.0f), 1332.0f);
        b3 = fminf(fmaxf(b3, 0.0f), 799.0f);

        dec[i] = make_float4(b0, b1, b2, b3);

        unsigned mono = 0u;
        if (score > SCORE_THRESH) mono = __float_as_uint(score) | 0x80000000u;
        sk[t] = ((u64)mono << 32) | (u64)(unsigned)(NBOX - 1 - t);
    }
    __syncthreads();

    for (int k = 2; k <= NBOX; k <<= 1) {
        for (int j = k >> 1; j > 0; j >>= 1) {
            for (int i = threadIdx.x; i < NBOX; i += 256) {
                int ixj = i ^ j;
                if (ixj > i) {
                    u64 a = sk[i];
                    u64 b = sk[ixj];
                    bool desc = ((i & k) == 0);
                    bool sw = desc ? (a < b) : (a > b);
                    if (sw) { sk[i] = b; sk[ixj] = a; }
                }
            }
            __syncthreads();
        }
    }

    for (int t = threadIdx.x; t < NBOX; t += 256) {
        u64 key = sk[t];
        keys_out[c * NBOX + t] = key;
        int idx = (NBOX - 1) - (int)(key & 0xFFFFFFFFull);
        int orig = c * NBOX + idx;
        float4 b = dec[orig];   // same block wrote dec before the barrier
        sbox4[c * NBOX + t] = b;
        {
#pragma clang fp contract(off)
            sarea[c * NBOX + t] = (b.z - b.x) * (b.w - b.y);
        }
    }
}

// ---------------- Kernel 2: IoU bitmask (balanced upper-tri) ----------------
__global__ __launch_bounds__(256) void mask_kernel(
    const float4* __restrict__ sbox4,
    const float* __restrict__ sarea,
    u64* __restrict__ mask,
    u64* __restrict__ diag)
{
    int c = blockIdx.x >> 4;
    int p = blockIdx.x & 15;
    __shared__ float4 box[NBOX];   // 32 KB
    __shared__ float  area[NBOX];  // 8 KB

    for (int i = threadIdx.x; i < NBOX; i += 256) {
        box[i]  = sbox4[c * NBOX + i];
        area[i] = sarea[c * NBOX + i];
    }
    __syncthreads();

    int r = threadIdx.x & 63;
    int g = threadIdx.x >> 6;

    for (int pass = 0; pass < 2; pass++) {
        int I = pass ? (31 - p) : p;
        int row = I * 64 + r;
        float4 rb = box[row];
        float rar = area[row];
        u64* mrow = mask + ((size_t)c * NBOX + row) * NCHUNK;

        for (int J = g; J < NCHUNK; J += 4) {
            u64 w = 0;
            if (J >= I) {
                int cbase = J * 64;
#pragma unroll 8
                for (int j2 = 0; j2 < 64; j2++) {
                    int col = cbase + j2;
                    float4 cb = box[col];          // wave-uniform -> LDS broadcast
                    float iou = iou_f(rb.x, rb.y, rb.z, rb.w, rar,
                                      cb.x, cb.y, cb.z, cb.w, area[col]);
                    if (col > row && iou > NMS_THRESH) w |= 1ull << j2;
                }
            }
            mrow[J] = w;
            if (J == I) diag[((size_t)c * NCHUNK + I) * 64 + r] = w;
        }
    }
}

// ---------------- Kernel 3: greedy resolve, register-prefetch pipeline ----------------
// Thread (r0=tid>>5, j=tid&31) holds chunk-I mask words for rows {r0,r0+8,..,r0+56},
// word j, in registers (double-buffered). Chunk I+1 loads issue at the top of
// iteration I and overlap the scan + OR phases.
__global__ __launch_bounds__(256) void resolve_kernel(
    const u64* __restrict__ keys,
    const u64* __restrict__ mask,
    const u64* __restrict__ diag,
    unsigned* __restrict__ keepbits)
{
    int c = blockIdx.x;
    int tid = threadIdx.x;
    __shared__ u64 lds_sup[NCHUNK];
    __shared__ u64 lds_kept;
    const u64* M = mask + (size_t)c * NBOX * NCHUNK;
    const u64* D = diag + (size_t)c * NCHUNK * 64;
    const u64* K = keys + (size_t)c * NBOX;

    int j  = tid & 31;
    int r0 = tid >> 5;          // 0..7

    if (tid < NCHUNK) lds_sup[tid] = 0ull;

    u64 mwA[8], mwB[8];
#pragma unroll
    for (int q = 0; q < 8; q++)
        mwA[q] = M[(size_t)(r0 + 8 * q) * NCHUNK + j];
    u64 keyA = 0, diagA = 0, keyB = 0, diagB = 0;
    if (tid < 64) { keyA = K[tid]; diagA = D[tid]; }
    __syncthreads();

    for (int I = 0; I < NCHUNK; I++) {
        // prefetch chunk I+1 (overlaps scan + OR below)
        if (I + 1 < NCHUNK) {
#pragma unroll
            for (int q = 0; q < 8; q++)
                mwB[q] = M[(size_t)((I + 1) * 64 + r0 + 8 * q) * NCHUNK + j];
            if (tid < 64) {
                keyB  = K[(I + 1) * 64 + tid];
                diagB = D[(I + 1) * 64 + tid];
            }
        }

        if (tid < 64) {
            unsigned mono = (unsigned)(keyA >> 32);
            u64 vI = __ballot(mono != 0u);
            u64 avail = vI & ~lds_sup[I];
            u64 kept = 0;
#pragma unroll
            for (int i = 0; i < 64; i++) {             // scalar greedy scan
                u64 m = 1ull << i;
                u64 row_i = __shfl(diagA, i);          // literal lane -> readlane
                if (avail & m) { kept |= m; avail &= ~row_i; }
            }
            int orig = c * NBOX + (NBOX - 1) - (int)(keyA & 0xFFFFFFFFull);
            keepbits[orig] = ((kept >> tid) & 1ull) ? (mono & 0x7FFFFFFFu) : 0u;
            if (tid == 0) lds_kept = kept;
        }
        __syncthreads();

        u64 kept = lds_kept;
#pragma unroll
        for (int q = 0; q < 8; q++) {
            if ((kept >> (r0 + 8 * q)) & 1ull) {
                if (mwA[q]) atomicOr(&lds_sup[j], mwA[q]);
            }
        }
        __syncthreads();

#pragma unroll
        for (int q = 0; q < 8; q++) mwA[q] = mwB[q];
        keyA = keyB; diagA = diagB;
    }
}

// ---------------- Kernel 4: count + exact 3-pass radix-select of kth ----------------
// Bit fields: [31:21] (2048 bins), [20:10] (2048 bins), [9:0] (1024 bins).
__global__ __launch_bounds__(1024) void select_kernel(
    const unsigned* __restrict__ keepbits,
    int* __restrict__ stats)   // stats[0]=n_det, stats[1]=kth bits
{
    __shared__ int hist[2048];
    __shared__ int gsum[64];
    __shared__ int s_cnt;
    __shared__ unsigned s_prefix;   // accumulated high bits
    __shared__ int s_rank;
    int tid = threadIdx.x;
    const uint4* kb4 = (const uint4*)keepbits;

    // ---- pass 1: bits [31:21] + count ----
    for (int b = tid; b < 2048; b += 1024) hist[b] = 0;
    if (tid == 0) s_cnt = 0;
    __syncthreads();
    int cnt = 0;
    for (int i = tid; i < NTOT / 4; i += 1024) {
        uint4 v = kb4[i];
        if (v.x) { cnt++; atomicAdd(&hist[v.x >> 21], 1); }
        if (v.y) { cnt++; atomicAdd(&hist[v.y >> 21], 1); }
        if (v.z) { cnt++; atomicAdd(&hist[v.z >> 21], 1); }
        if (v.w) { cnt++; atomicAdd(&hist[v.w >> 21], 1); }
    }
    atomicAdd(&s_cnt, cnt);
    __syncthreads();
    int n_det = s_cnt;

    if (n_det > DETS_PER_IMG) {
        // find bin holding the 100th largest (two-level scan)
        if (tid < 64) {
            int s = 0;
            for (int t = 0; t < 32; t++) s += hist[tid * 32 + t];
            gsum[tid] = s;
        }
        __syncthreads();
        if (tid == 0) {
            int r = DETS_PER_IMG;
            int g = 63;
            for (; g > 0; g--) { if (r <= gsum[g]) break; r -= gsum[g]; }
            int b = g * 32 + 31;
            for (; b > g * 32; b--) { if (r <= hist[b]) break; r -= hist[b]; }
            s_prefix = (unsigned)b << 21;
            s_rank = r;
        }
        __syncthreads();

        // ---- pass 2: bits [20:10] among matching top-11 ----
        unsigned p1 = s_prefix;
        for (int b = tid; b < 2048; b += 1024) hist[b] = 0;
        __syncthreads();
        for (int i = tid; i < NTOT / 4; i += 1024) {
            uint4 v = kb4[i];
            if (v.x && (v.x >> 21 << 21) == p1) atomicAdd(&hist[(v.x >> 10) & 2047], 1);
            if (v.y && (v.y >> 21 << 21) == p1) atomicAdd(&hist[(v.y >> 10) & 2047], 1);
            if (v.z && (v.z >> 21 << 21) == p1) atomicAdd(&hist[(v.z >> 10) & 2047], 1);
            if (v.w && (v.w >> 21 << 21) == p1) atomicAdd(&hist[(v.w >> 10) & 2047], 1);
        }
        __syncthreads();
        if (tid < 64) {
            int s = 0;
            for (int t = 0; t < 32; t++) s += hist[tid * 32 + t];
            gsum[tid] = s;
        }
        __syncthreads();
        if (tid == 0) {
            int r = s_rank;
            int g = 63;
            for (; g > 0; g--) { if (r <= gsum[g]) break; r -= gsum[g]; }
            int b = g * 32 + 31;
            for (; b > g * 32; b--) { if (r <= hist[b]) break; r -= hist[b]; }
            s_prefix = p1 | ((unsigned)b << 10);
            s_rank = r;
        }
        __syncthreads();

        // ---- pass 3: bits [9:0] among matching top-22 ----
        unsigned p2 = s_prefix;
        for (int b = tid; b < 1024; b += 1024) hist[b] = 0;
        __syncthreads();
        for (int i = tid; i < NTOT / 4; i += 1024) {
            uint4 v = kb4[i];
            if (v.x && (v.x >> 10 << 10) == p2) atomicAdd(&hist[v.x & 1023], 1);
            if (v.y && (v.y >> 10 << 10) == p2) atomicAdd(&hist[v.y & 1023], 1);
            if (v.z && (v.z >> 10 << 10) == p2) atomicAdd(&hist[v.z & 1023], 1);
            if (v.w && (v.w >> 10 << 10) == p2) atomicAdd(&hist[v.w & 1023], 1);
        }
        __syncthreads();
        if (tid < 32) {
            int s = 0;
            for (int t = 0; t < 32; t++) s += hist[tid * 32 + t];
            gsum[tid] = s;
        }
        __syncthreads();
        if (tid == 0) {
            int r = s_rank;
            int g = 31;
            for (; g > 0; g--) { if (r <= gsum[g]) break; r -= gsum[g]; }
            int b = g * 32 + 31;
            for (; b > g * 32; b--) { if (r <= hist[b]) break; r -= hist[b]; }
            s_prefix = p2 | (unsigned)b;
        }
        __syncthreads();
    }

    if (tid == 0) {
        stats[0] = n_det;
        stats[1] = (n_det > DETS_PER_IMG) ? (int)s_prefix : 0;
    }
}

// ---------------- Kernel 5: final outputs ----------------
__global__ __launch_bounds__(256) void write_kernel(
    const unsigned* __restrict__ keepbits,
    const float4* __restrict__ dec,
    const int* __restrict__ stats,
    const int* __restrict__ ulabels,
    float* __restrict__ out)
{
    int i = blockIdx.x * blockDim.x + threadIdx.x;
    if (i >= NTOT) return;

    int n_det = stats[0];
    unsigned kth = (unsigned)stats[1];
    unsigned kb = keepbits[i];
    bool kf = kb && (n_det <= DETS_PER_IMG || kb >= kth);  // uint cmp == float cmp (positive)

    float4 b = dec[i];
    float* o5 = out + (size_t)i * 5;
    if (kf) {
        o5[0] = b.x; o5[1] = b.y; o5[2] = b.z; o5[3] = b.w;
        o5[4] = __uint_as_float(kb);
    } else {
        o5[0] = 0.0f; o5[1] = 0.0f; o5[2] = 0.0f; o5[3] = 0.0f; o5[4] = 0.0f;
    }

    int c = i >> 11;
    out[NTOT * 5 + i] = (float)ulabels[c];
    out[NTOT * 5 + NTOT + i] = kf ? 1.0f : 0.0f;
}

extern "C" void kernel_launch(void* const* d_in, const int* in_sizes, int n_in,
                              void* d_out, int out_size, void* d_ws, size_t ws_size,
                              hipStream_t stream) {
    (void)in_sizes; (void)n_in; (void)out_size; (void)ws_size;

    const float* class_logit    = (const float*)d_in[0];   // (NTOT,2)
    const float* box_regression = (const float*)d_in[1];   // (NTOT,8)
    const float* proposal_boxes = (const float*)d_in[2];   // (NBOX,4)
    const int*   unique_labels  = (const int*)d_in[3];     // (NCLS)

    char* ws = (char*)d_ws;
    float4* dec        = (float4*)(ws + 0);         // 524288
    u64* keys          = (u64*)(ws + 524288);       // 262144
    float4* sbox4      = (float4*)(ws + 786432);    // 524288
    float* sarea       = (float*)(ws + 1310720);    // 131072
    unsigned* keepbits = (unsigned*)(ws + 1441792); // 131072
    u64* diag          = (u64*)(ws + 1572864);      // 262144
    int* stats         = (int*)(ws + 1835008);      // 256
    u64* mask          = (u64*)(ws + 1835264);      // 8388608

    float* out = (float*)d_out;

    sortdecode_kernel<<<NCLS, 256, 0, stream>>>(class_logit, box_regression,
                                                proposal_boxes, dec, keys,
                                                sbox4, sarea);
    mask_kernel<<<NCLS * 16, 256, 0, stream>>>(sbox4, sarea, mask, diag);
    resolve_kernel<<<NCLS, 256, 0, stream>>>(keys, mask, diag, keepbits);
    select_kernel<<<1, 1024, 0, stream>>>(keepbits, stats);
    write_kernel<<<NTOT / 256, 256, 0, stream>>>(keepbits, dec, stats,
                                                 unique_labels, out);
}

// Round 6
// 276.694 us; speedup vs baseline: 6.9676x; 1.0993x over previous
//
#include <hip/hip_runtime.h>
#include <hip/hip_bf16.h>

#define NCLS 16
#define NBOX 2048
#define NTOT (NCLS * NBOX)
#define NCHUNK 32                 /* NBOX / 64 */
#define SCORE_THRESH 0.05f
#define NMS_THRESH 0.5f
#define DETS_PER_IMG 100
#define BBOX_CLIP 4.135166556742356f  /* log(1000/16) */

typedef unsigned long long u64;

// IoU identical (op order) to the reference; symmetric in the two boxes.
__device__ __forceinline__ float iou_f(float x1, float y1, float x2, float y2, float ar,
                                       float X1, float Y1, float X2, float Y2, float AR) {
#pragma clang fp contract(off)
    float lx = fmaxf(x1, X1);
    float ly = fmaxf(y1, Y1);
    float rx = fminf(x2, X2);
    float ry = fminf(y2, Y2);
    float w = fmaxf(rx - lx, 0.0f);
    float h = fmaxf(ry - ly, 0.0f);
    float inter = w * h;
    return inter / (ar + AR - inter + 1e-12f);
}

// ---------------- Kernel 1: fused decode + per-class bitonic sort ----------------
__global__ __launch_bounds__(256) void sortdecode_kernel(
    const float* __restrict__ logits,   // (NTOT, 2)
    const float* __restrict__ regr,     // (NTOT, 8)
    const float* __restrict__ props,    // (NBOX, 4)
    float4* __restrict__ dec,           // (NTOT)
    u64* __restrict__ keys_out,         // (NTOT)
    float4* __restrict__ sbox4,         // (NTOT) sorted boxes
    float* __restrict__ sarea)          // (NTOT) sorted areas
{
    int c = blockIdx.x;
    __shared__ u64 sk[NBOX];

    for (int t = threadIdx.x; t < NBOX; t += 256) {
#pragma clang fp contract(off)
        int i = c * NBOX + t;
        float x0 = logits[2 * i + 0];
        float x1 = logits[2 * i + 1];
        float m = fmaxf(x0, x1);
        float e0 = expf(x0 - m);
        float e1 = expf(x1 - m);
        float score = e1 / (e0 + e1);

        float px1 = props[4 * t + 0];
        float py1 = props[4 * t + 1];
        float px2 = props[4 * t + 2];
        float py2 = props[4 * t + 3];

        float w  = px2 - px1 + 1.0f;
        float h  = py2 - py1 + 1.0f;
        float cx = px1 + 0.5f * w;
        float cy = py1 + 0.5f * h;

        float dx = regr[8 * i + 4] / 10.0f;
        float dy = regr[8 * i + 5] / 10.0f;
        float dw = fminf(regr[8 * i + 6] / 5.0f, BBOX_CLIP);
        float dh = fminf(regr[8 * i + 7] / 5.0f, BBOX_CLIP);

        float pcx = dx * w + cx;
        float pcy = dy * h + cy;
        float pw  = expf(dw) * w;
        float ph  = expf(dh) * h;

        float b0 = pcx - 0.5f * pw;
        float b1 = pcy - 0.5f * ph;
        float b2 = pcx + 0.5f * pw - 1.0f;
        float b3 = pcy + 0.5f * ph - 1.0f;

        b0 = fminf(fmaxf(b0, 0.0f), 1332.0f);
        b1 = fminf(fmaxf(b1, 0.0f), 799.0f);
        b2 = fminf(fmaxf(b2, 0.0f), 1332.0f);
        b3 = fminf(fmaxf(b3, 0.0f), 799.0f);

        dec[i] = make_float4(b0, b1, b2, b3);

        unsigned mono = 0u;
        if (score > SCORE_THRESH) mono = __float_as_uint(score) | 0x80000000u;
        sk[t] = ((u64)mono << 32) | (u64)(unsigned)(NBOX - 1 - t);
    }
    __syncthreads();

    for (int k = 2; k <= NBOX; k <<= 1) {
        for (int j = k >> 1; j > 0; j >>= 1) {
            for (int i = threadIdx.x; i < NBOX; i += 256) {
                int ixj = i ^ j;
                if (ixj > i) {
                    u64 a = sk[i];
                    u64 b = sk[ixj];
                    bool desc = ((i & k) == 0);
                    bool sw = desc ? (a < b) : (a > b);
                    if (sw) { sk[i] = b; sk[ixj] = a; }
                }
            }
            __syncthreads();
        }
    }

    for (int t = threadIdx.x; t < NBOX; t += 256) {
        u64 key = sk[t];
        keys_out[c * NBOX + t] = key;
        int idx = (NBOX - 1) - (int)(key & 0xFFFFFFFFull);
        int orig = c * NBOX + idx;
        float4 b = dec[orig];   // same block wrote dec before the barrier
        sbox4[c * NBOX + t] = b;
        {
#pragma clang fp contract(off)
            sarea[c * NBOX + t] = (b.z - b.x) * (b.w - b.y);
        }
    }
}

// ---------------- Kernel 2: transposed IoU bitmask ----------------
// maskT[c][I][j] = u64 over rows i2 of chunk I: bit set iff global row
// (I*64+i2) < j  &&  IoU(row, col j) > thresh. Layout coalesced in j.
// Words with I > chunk(j) are never read -> not written.
__global__ __launch_bounds__(256) void mask_kernel(
    const float4* __restrict__ sbox4,
    const float* __restrict__ sarea,
    u64* __restrict__ maskT)
{
    int c = blockIdx.x >> 4;
    int p = blockIdx.x & 15;
    __shared__ float4 box[NBOX];   // 32 KB
    __shared__ float  area[NBOX];  // 8 KB

    for (int i = threadIdx.x; i < NBOX; i += 256) {
        box[i]  = sbox4[c * NBOX + i];
        area[i] = sarea[c * NBOX + i];
    }
    __syncthreads();

    int r = threadIdx.x & 63;   // column lane
    int g = threadIdx.x >> 6;   // row-chunk group

    for (int pass = 0; pass < 2; pass++) {
        int Jc = pass ? (31 - p) : p;     // column chunk (balanced pairing)
        int j = Jc * 64 + r;              // global sorted column index
        float4 jb = box[j];
        float jar = area[j];

        for (int I = g; I <= Jc; I += 4) {
            u64 w = 0;
            int rbase = I * 64;
#pragma unroll 8
            for (int i2 = 0; i2 < 64; i2++) {
                int gi = rbase + i2;
                float4 rb = box[gi];           // wave-uniform -> LDS broadcast
                float iou = iou_f(rb.x, rb.y, rb.z, rb.w, area[gi],
                                  jb.x, jb.y, jb.z, jb.w, jar);
                if (gi < j && iou > NMS_THRESH) w |= 1ull << i2;
            }
            maskT[((size_t)c * NCHUNK + I) * NBOX + j] = w;   // coalesced in j
        }
    }
}

// ---------------- Kernel 3: greedy resolve, column formulation ----------------
// 1024 threads/class; thread owns boxes tid (chunk wv) and tid+1024 (chunk wv+16),
// suppressed-flags in registers. Per chunk: owning wave scans (ballot bit-transpose,
// wave-uniform SALU greedy), one barrier, then every thread ANDs its prefetched
// maskT word with the kept mask. One barrier per chunk, no LDS atomics.
__global__ __launch_bounds__(1024) void resolve_kernel(
    const u64* __restrict__ keys,
    const u64* __restrict__ maskT,
    unsigned* __restrict__ keepbits)
{
    int c = blockIdx.x;
    int tid = threadIdx.x;
    int wv = tid >> 6;
    int ln = tid & 63;
    __shared__ u64 keptArr[NCHUNK];
    const u64* MT = maskT + (size_t)c * NCHUNK * NBOX;
    const u64* K  = keys + (size_t)c * NBOX;

    u64 k0 = K[tid];
    u64 k1 = K[tid + 1024];
    unsigned mono0 = (unsigned)(k0 >> 32);
    unsigned mono1 = (unsigned)(k1 >> 32);
    bool val0 = (mono0 != 0u), val1 = (mono1 != 0u);
    bool sup0 = false, sup1 = false;

    // chunk-0 words (box0 needs it only if wv>=0 -> always for chunk 0)
    u64 wA0 = MT[tid];                 // chunk(box0)=wv >= 0
    u64 wA1 = MT[tid + 1024];          // chunk(box1)=wv+16 >= 0
    u64 wB0 = 0, wB1 = 0;

    for (int I = 0; I < NCHUNK; I++) {
        // prefetch chunk I+1 (skip provably-zero words: I+1 > chunk(box))
        if (I + 1 < NCHUNK) {
            wB0 = (I + 1 <= wv)      ? MT[(size_t)(I + 1) * NBOX + tid]        : 0ull;
            wB1 = (I + 1 <= wv + 16) ? MT[(size_t)(I + 1) * NBOX + tid + 1024] : 0ull;
        }

        int owner = I & 15;
        int slot  = I >> 4;
        if (wv == owner) {
            u64 myw = slot ? wA1 : wA0;
            bool av = slot ? (val1 && !sup1) : (val0 && !sup0);
            u64 avail = __ballot(av);
            u64 kept = 0;
#pragma unroll
            for (int i = 0; i < 64; i++) {
                u64 row = __ballot((myw >> i) & 1ull);   // in-wave bit transpose
                if ((avail >> i) & 1ull) { kept |= 1ull << i; avail &= ~row; }
            }
            if (ln == 0) keptArr[I] = kept;
        }
        __syncthreads();

        u64 kept = keptArr[I];
        sup0 = sup0 || ((wA0 & kept) != 0ull);
        sup1 = sup1 || ((wA1 & kept) != 0ull);
        wA0 = wB0; wA1 = wB1;
    }

    int orig0 = c * NBOX + (NBOX - 1) - (int)(k0 & 0xFFFFFFFFull);
    int orig1 = c * NBOX + (NBOX - 1) - (int)(k1 & 0xFFFFFFFFull);
    keepbits[orig0] = ((keptArr[wv] >> ln) & 1ull) ? (mono0 & 0x7FFFFFFFu) : 0u;
    keepbits[orig1] = ((keptArr[wv + 16] >> ln) & 1ull) ? (mono1 & 0x7FFFFFFFu) : 0u;
}

// ---------------- Kernel 4: count + exact 3-pass radix-select of kth ----------------
__global__ __launch_bounds__(1024) void select_kernel(
    const unsigned* __restrict__ keepbits,
    int* __restrict__ stats)   // stats[0]=n_det, stats[1]=kth bits
{
    __shared__ int hist[2048];
    __shared__ int gsum[64];
    __shared__ int s_cnt;
    __shared__ unsigned s_prefix;
    __shared__ int s_rank;
    int tid = threadIdx.x;
    const uint4* kb4 = (const uint4*)keepbits;

    for (int b = tid; b < 2048; b += 1024) hist[b] = 0;
    if (tid == 0) s_cnt = 0;
    __syncthreads();
    int cnt = 0;
    for (int i = tid; i < NTOT / 4; i += 1024) {
        uint4 v = kb4[i];
        if (v.x) { cnt++; atomicAdd(&hist[v.x >> 21], 1); }
        if (v.y) { cnt++; atomicAdd(&hist[v.y >> 21], 1); }
        if (v.z) { cnt++; atomicAdd(&hist[v.z >> 21], 1); }
        if (v.w) { cnt++; atomicAdd(&hist[v.w >> 21], 1); }
    }
    atomicAdd(&s_cnt, cnt);
    __syncthreads();
    int n_det = s_cnt;

    if (n_det > DETS_PER_IMG) {
        if (tid < 64) {
            int s = 0;
            for (int t = 0; t < 32; t++) s += hist[tid * 32 + t];
            gsum[tid] = s;
        }
        __syncthreads();
        if (tid == 0) {
            int r = DETS_PER_IMG;
            int g = 63;
            for (; g > 0; g--) { if (r <= gsum[g]) break; r -= gsum[g]; }
            int b = g * 32 + 31;
            for (; b > g * 32; b--) { if (r <= hist[b]) break; r -= hist[b]; }
            s_prefix = (unsigned)b << 21;
            s_rank = r;
        }
        __syncthreads();

        unsigned p1 = s_prefix;
        for (int b = tid; b < 2048; b += 1024) hist[b] = 0;
        __syncthreads();
        for (int i = tid; i < NTOT / 4; i += 1024) {
            uint4 v = kb4[i];
            if (v.x && (v.x >> 21 << 21) == p1) atomicAdd(&hist[(v.x >> 10) & 2047], 1);
            if (v.y && (v.y >> 21 << 21) == p1) atomicAdd(&hist[(v.y >> 10) & 2047], 1);
            if (v.z && (v.z >> 21 << 21) == p1) atomicAdd(&hist[(v.z >> 10) & 2047], 1);
            if (v.w && (v.w >> 21 << 21) == p1) atomicAdd(&hist[(v.w >> 10) & 2047], 1);
        }
        __syncthreads();
        if (tid < 64) {
            int s = 0;
            for (int t = 0; t < 32; t++) s += hist[tid * 32 + t];
            gsum[tid] = s;
        }
        __syncthreads();
        if (tid == 0) {
            int r = s_rank;
            int g = 63;
            for (; g > 0; g--) { if (r <= gsum[g]) break; r -= gsum[g]; }
            int b = g * 32 + 31;
            for (; b > g * 32; b--) { if (r <= hist[b]) break; r -= hist[b]; }
            s_prefix = p1 | ((unsigned)b << 10);
            s_rank = r;
        }
        __syncthreads();

        unsigned p2 = s_prefix;
        for (int b = tid; b < 1024; b += 1024) hist[b] = 0;
        __syncthreads();
        for (int i = tid; i < NTOT / 4; i += 1024) {
            uint4 v = kb4[i];
            if (v.x && (v.x >> 10 << 10) == p2) atomicAdd(&hist[v.x & 1023], 1);
            if (v.y && (v.y >> 10 << 10) == p2) atomicAdd(&hist[v.y & 1023], 1);
            if (v.z && (v.z >> 10 << 10) == p2) atomicAdd(&hist[v.z & 1023], 1);
            if (v.w && (v.w >> 10 << 10) == p2) atomicAdd(&hist[v.w & 1023], 1);
        }
        __syncthreads();
        if (tid < 32) {
            int s = 0;
            for (int t = 0; t < 32; t++) s += hist[tid * 32 + t];
            gsum[tid] = s;
        }
        __syncthreads();
        if (tid == 0) {
            int r = s_rank;
            int g = 31;
            for (; g > 0; g--) { if (r <= gsum[g]) break; r -= gsum[g]; }
            int b = g * 32 + 31;
            for (; b > g * 32; b--) { if (r <= hist[b]) break; r -= hist[b]; }
            s_prefix = p2 | (unsigned)b;
        }
        __syncthreads();
    }

    if (tid == 0) {
        stats[0] = n_det;
        stats[1] = (n_det > DETS_PER_IMG) ? (int)s_prefix : 0;
    }
}

// ---------------- Kernel 5: final outputs ----------------
__global__ __launch_bounds__(256) void write_kernel(
    const unsigned* __restrict__ keepbits,
    const float4* __restrict__ dec,
    const int* __restrict__ stats,
    const int* __restrict__ ulabels,
    float* __restrict__ out)
{
    int i = blockIdx.x * blockDim.x + threadIdx.x;
    if (i >= NTOT) return;

    int n_det = stats[0];
    unsigned kth = (unsigned)stats[1];
    unsigned kb = keepbits[i];
    bool kf = kb && (n_det <= DETS_PER_IMG || kb >= kth);  // uint cmp == float cmp (positive)

    float4 b = dec[i];
    float* o5 = out + (size_t)i * 5;
    if (kf) {
        o5[0] = b.x; o5[1] = b.y; o5[2] = b.z; o5[3] = b.w;
        o5[4] = __uint_as_float(kb);
    } else {
        o5[0] = 0.0f; o5[1] = 0.0f; o5[2] = 0.0f; o5[3] = 0.0f; o5[4] = 0.0f;
    }

    int c = i >> 11;
    out[NTOT * 5 + i] = (float)ulabels[c];
    out[NTOT * 5 + NTOT + i] = kf ? 1.0f : 0.0f;
}

extern "C" void kernel_launch(void* const* d_in, const int* in_sizes, int n_in,
                              void* d_out, int out_size, void* d_ws, size_t ws_size,
                              hipStream_t stream) {
    (void)in_sizes; (void)n_in; (void)out_size; (void)ws_size;

    const float* class_logit    = (const float*)d_in[0];   // (NTOT,2)
    const float* box_regression = (const float*)d_in[1];   // (NTOT,8)
    const float* proposal_boxes = (const float*)d_in[2];   // (NBOX,4)
    const int*   unique_labels  = (const int*)d_in[3];     // (NCLS)

    char* ws = (char*)d_ws;
    float4* dec        = (float4*)(ws + 0);         // 524288
    u64* keys          = (u64*)(ws + 524288);       // 262144
    float4* sbox4      = (float4*)(ws + 786432);    // 524288
    float* sarea       = (float*)(ws + 1310720);    // 131072
    unsigned* keepbits = (unsigned*)(ws + 1441792); // 131072
    int* stats         = (int*)(ws + 1572864);      // 256
    u64* maskT         = (u64*)(ws + 1573120);      // 8388608

    float* out = (float*)d_out;

    sortdecode_kernel<<<NCLS, 256, 0, stream>>>(class_logit, box_regression,
                                                proposal_boxes, dec, keys,
                                                sbox4, sarea);
    mask_kernel<<<NCLS * 16, 256, 0, stream>>>(sbox4, sarea, maskT);
    resolve_kernel<<<NCLS, 1024, 0, stream>>>(keys, maskT, keepbits);
    select_kernel<<<1, 1024, 0, stream>>>(keepbits, stats);
    write_kernel<<<NTOT / 256, 256, 0, stream>>>(keepbits, dec, stats,
                                                 unique_labels, out);
}

// Round 7
// 221.594 us; speedup vs baseline: 8.7002x; 1.2487x over previous
//
#include <hip/hip_runtime.h>
#include <hip/hip_bf16.h>

#define NCLS 16
#define NBOX 2048
#define NTOT (NCLS * NBOX)
#define NCHUNK 32                 /* NBOX / 64 */
#define SCORE_THRESH 0.05f
#define NMS_THRESH 0.5f
#define DETS_PER_IMG 100
#define BBOX_CLIP 4.135166556742356f  /* log(1000/16) */

typedef unsigned long long u64;

// IoU identical (op order) to the reference; symmetric in the two boxes.
__device__ __forceinline__ float iou_f(float x1, float y1, float x2, float y2, float ar,
                                       float X1, float Y1, float X2, float Y2, float AR) {
#pragma clang fp contract(off)
    float lx = fmaxf(x1, X1);
    float ly = fmaxf(y1, Y1);
    float rx = fminf(x2, X2);
    float ry = fminf(y2, Y2);
    float w = fmaxf(rx - lx, 0.0f);
    float h = fmaxf(ry - ly, 0.0f);
    float inter = w * h;
    return inter / (ar + AR - inter + 1e-12f);
}

__device__ __forceinline__ u64 sel_mx(u64 a, u64 b, bool keepmax) {
    u64 mx = (a > b) ? a : b;
    u64 mn = (a > b) ? b : a;
    return keepmax ? mx : mn;
}

// ---------------- Kernel 1: fused decode + register-resident bitonic sort ----
// 1024 threads. Wave w holds positions [128w,128w+128): lane l keeps e0=pos
// 128w+l, e1=pos 128w+64+l in registers. Network identical to the classic
// (k,j) bitonic; j<64 via shfl_xor, j==64 in-thread, j>=128 via LDS (10 steps).
__global__ __launch_bounds__(1024) void sortdecode_kernel(
    const float* __restrict__ logits,   // (NTOT, 2)
    const float* __restrict__ regr,     // (NTOT, 8)
    const float* __restrict__ props,    // (NBOX, 4)
    float4* __restrict__ dec,           // (NTOT)
    u64* __restrict__ keys_out,         // (NTOT)
    float4* __restrict__ sbox4,         // (NTOT) sorted boxes
    float* __restrict__ sarea)          // (NTOT) sorted areas
{
    int c = blockIdx.x;
    int tid = threadIdx.x;
    int w = tid >> 6, l = tid & 63;
    int p0 = w * 128 + l;
    int p1 = p0 + 64;
    __shared__ u64 sk[NBOX];

    // ---- decode elements p0, p1 directly into registers ----
    u64 e01[2];
#pragma unroll
    for (int s = 0; s < 2; s++) {
#pragma clang fp contract(off)
        int t = s ? p1 : p0;
        int i = c * NBOX + t;
        float x0 = logits[2 * i + 0];
        float x1 = logits[2 * i + 1];
        float m = fmaxf(x0, x1);
        float e0f = expf(x0 - m);
        float e1f = expf(x1 - m);
        float score = e1f / (e0f + e1f);

        float px1 = props[4 * t + 0];
        float py1 = props[4 * t + 1];
        float px2 = props[4 * t + 2];
        float py2 = props[4 * t + 3];

        float bw = px2 - px1 + 1.0f;
        float bh = py2 - py1 + 1.0f;
        float cx = px1 + 0.5f * bw;
        float cy = py1 + 0.5f * bh;

        float dx = regr[8 * i + 4] / 10.0f;
        float dy = regr[8 * i + 5] / 10.0f;
        float dw = fminf(regr[8 * i + 6] / 5.0f, BBOX_CLIP);
        float dh = fminf(regr[8 * i + 7] / 5.0f, BBOX_CLIP);

        float pcx = dx * bw + cx;
        float pcy = dy * bh + cy;
        float pw  = expf(dw) * bw;
        float ph  = expf(dh) * bh;

        float b0 = pcx - 0.5f * pw;
        float b1 = pcy - 0.5f * ph;
        float b2 = pcx + 0.5f * pw - 1.0f;
        float b3 = pcy + 0.5f * ph - 1.0f;

        b0 = fminf(fmaxf(b0, 0.0f), 1332.0f);
        b1 = fminf(fmaxf(b1, 0.0f), 799.0f);
        b2 = fminf(fmaxf(b2, 0.0f), 1332.0f);
        b3 = fminf(fmaxf(b3, 0.0f), 799.0f);

        dec[i] = make_float4(b0, b1, b2, b3);

        unsigned mono = 0u;
        if (score > SCORE_THRESH) mono = __float_as_uint(score) | 0x80000000u;
        e01[s] = ((u64)mono << 32) | (u64)(unsigned)(NBOX - 1 - t);
    }
    u64 e0 = e01[0], e1 = e01[1];

    // ---- bitonic network (descending overall) ----
    for (int k = 2; k <= NBOX; k <<= 1) {
        bool desc0 = (p0 & k) == 0;   // same as (p1 & k) == 0 for k >= 128;
        bool desc1 = (p1 & k) == 0;   // differs only when k == 64
        for (int j = k >> 1; j > 0; j >>= 1) {
            if (j >= 128) {
                sk[p0] = e0; sk[p1] = e1;
                __syncthreads();
                u64 q0 = sk[p0 ^ j];
                u64 q1 = sk[p1 ^ j];
                e0 = sel_mx(e0, q0, desc0 ^ ((p0 & j) != 0));
                e1 = sel_mx(e1, q1, desc1 ^ ((p1 & j) != 0));
                __syncthreads();
            } else if (j == 64) {
                // pair (p0,p1): p0 < p1, desc at p0
                u64 mx = (e0 > e1) ? e0 : e1;
                u64 mn = (e0 > e1) ? e1 : e0;
                e0 = desc0 ? mx : mn;
                e1 = desc0 ? mn : mx;
            } else {
                u64 q0 = __shfl_xor(e0, j);
                u64 q1 = __shfl_xor(e1, j);
                bool hi = (l & j) != 0;
                e0 = sel_mx(e0, q0, desc0 ^ hi);
                e1 = sel_mx(e1, q1, desc1 ^ hi);
            }
        }
    }

    sk[p0] = e0; sk[p1] = e1;
    __syncthreads();

    // ---- emit sorted keys + SoA (gather dec written above; block-local) ----
    for (int t = tid; t < NBOX; t += 1024) {
        u64 key = sk[t];
        keys_out[c * NBOX + t] = key;
        int idx = (NBOX - 1) - (int)(key & 0xFFFFFFFFull);
        int orig = c * NBOX + idx;
        float4 b = dec[orig];
        sbox4[c * NBOX + t] = b;
        {
#pragma clang fp contract(off)
            sarea[c * NBOX + t] = (b.z - b.x) * (b.w - b.y);
        }
    }
}

// ---------------- Kernel 2: transposed IoU bitmask ----------------
// maskT[c][I][j] = u64 over rows i2 of chunk I: bit set iff global row
// (I*64+i2) < j  &&  IoU(row, col j) > thresh. Layout coalesced in j.
__global__ __launch_bounds__(256) void mask_kernel(
    const float4* __restrict__ sbox4,
    const float* __restrict__ sarea,
    u64* __restrict__ maskT)
{
    int c = blockIdx.x >> 4;
    int p = blockIdx.x & 15;
    __shared__ float4 box[NBOX];   // 32 KB
    __shared__ float  area[NBOX];  // 8 KB

    for (int i = threadIdx.x; i < NBOX; i += 256) {
        box[i]  = sbox4[c * NBOX + i];
        area[i] = sarea[c * NBOX + i];
    }
    __syncthreads();

    int r = threadIdx.x & 63;   // column lane
    int g = threadIdx.x >> 6;   // row-chunk group

    for (int pass = 0; pass < 2; pass++) {
        int Jc = pass ? (31 - p) : p;     // column chunk (balanced pairing)
        int j = Jc * 64 + r;              // global sorted column index
        float4 jb = box[j];
        float jar = area[j];

        for (int I = g; I <= Jc; I += 4) {
            u64 w = 0;
            int rbase = I * 64;
#pragma unroll 8
            for (int i2 = 0; i2 < 64; i2++) {
                int gi = rbase + i2;
                float4 rb = box[gi];           // wave-uniform -> LDS broadcast
                float iou = iou_f(rb.x, rb.y, rb.z, rb.w, area[gi],
                                  jb.x, jb.y, jb.z, jb.w, jar);
                if (gi < j && iou > NMS_THRESH) w |= 1ull << i2;
            }
            maskT[((size_t)c * NCHUNK + I) * NBOX + j] = w;   // coalesced in j
        }
    }
}

// ---------------- Kernel 3: greedy resolve, column formulation ----------------
__global__ __launch_bounds__(1024) void resolve_kernel(
    const u64* __restrict__ keys,
    const u64* __restrict__ maskT,
    unsigned* __restrict__ keepbits)
{
    int c = blockIdx.x;
    int tid = threadIdx.x;
    int wv = tid >> 6;
    int ln = tid & 63;
    __shared__ u64 keptArr[NCHUNK];
    const u64* MT = maskT + (size_t)c * NCHUNK * NBOX;
    const u64* K  = keys + (size_t)c * NBOX;

    u64 k0 = K[tid];
    u64 k1 = K[tid + 1024];
    unsigned mono0 = (unsigned)(k0 >> 32);
    unsigned mono1 = (unsigned)(k1 >> 32);
    bool val0 = (mono0 != 0u), val1 = (mono1 != 0u);
    bool sup0 = false, sup1 = false;

    u64 wA0 = MT[tid];
    u64 wA1 = MT[tid + 1024];
    u64 wB0 = 0, wB1 = 0;

    for (int I = 0; I < NCHUNK; I++) {
        if (I + 1 < NCHUNK) {
            wB0 = (I + 1 <= wv)      ? MT[(size_t)(I + 1) * NBOX + tid]        : 0ull;
            wB1 = (I + 1 <= wv + 16) ? MT[(size_t)(I + 1) * NBOX + tid + 1024] : 0ull;
        }

        int owner = I & 15;
        int slot  = I >> 4;
        if (wv == owner) {
            u64 myw = slot ? wA1 : wA0;
            bool av = slot ? (val1 && !sup1) : (val0 && !sup0);
            u64 avail = __ballot(av);
            u64 kept = 0;
#pragma unroll
            for (int i = 0; i < 64; i++) {
                u64 row = __ballot((myw >> i) & 1ull);   // in-wave bit transpose
                if ((avail >> i) & 1ull) { kept |= 1ull << i; avail &= ~row; }
            }
            if (ln == 0) keptArr[I] = kept;
        }
        __syncthreads();

        u64 kept = keptArr[I];
        sup0 = sup0 || ((wA0 & kept) != 0ull);
        sup1 = sup1 || ((wA1 & kept) != 0ull);
        wA0 = wB0; wA1 = wB1;
    }

    int orig0 = c * NBOX + (NBOX - 1) - (int)(k0 & 0xFFFFFFFFull);
    int orig1 = c * NBOX + (NBOX - 1) - (int)(k1 & 0xFFFFFFFFull);
    keepbits[orig0] = ((keptArr[wv] >> ln) & 1ull) ? (mono0 & 0x7FFFFFFFu) : 0u;
    keepbits[orig1] = ((keptArr[wv + 16] >> ln) & 1ull) ? (mono1 & 0x7FFFFFFFu) : 0u;
}

// ---------------- Kernel 4: count + exact 3-pass radix-select of kth ----------------
__global__ __launch_bounds__(1024) void select_kernel(
    const unsigned* __restrict__ keepbits,
    int* __restrict__ stats)   // stats[0]=n_det, stats[1]=kth bits
{
    __shared__ int hist[2048];
    __shared__ int gsum[64];
    __shared__ int s_cnt;
    __shared__ unsigned s_prefix;
    __shared__ int s_rank;
    int tid = threadIdx.x;
    const uint4* kb4 = (const uint4*)keepbits;

    for (int b = tid; b < 2048; b += 1024) hist[b] = 0;
    if (tid == 0) s_cnt = 0;
    __syncthreads();
    int cnt = 0;
    for (int i = tid; i < NTOT / 4; i += 1024) {
        uint4 v = kb4[i];
        if (v.x) { cnt++; atomicAdd(&hist[v.x >> 21], 1); }
        if (v.y) { cnt++; atomicAdd(&hist[v.y >> 21], 1); }
        if (v.z) { cnt++; atomicAdd(&hist[v.z >> 21], 1); }
        if (v.w) { cnt++; atomicAdd(&hist[v.w >> 21], 1); }
    }
    atomicAdd(&s_cnt, cnt);
    __syncthreads();
    int n_det = s_cnt;

    if (n_det > DETS_PER_IMG) {
        if (tid < 64) {
            int s = 0;
            for (int t = 0; t < 32; t++) s += hist[tid * 32 + t];
            gsum[tid] = s;
        }
        __syncthreads();
        if (tid == 0) {
            int r = DETS_PER_IMG;
            int g = 63;
            for (; g > 0; g--) { if (r <= gsum[g]) break; r -= gsum[g]; }
            int b = g * 32 + 31;
            for (; b > g * 32; b--) { if (r <= hist[b]) break; r -= hist[b]; }
            s_prefix = (unsigned)b << 21;
            s_rank = r;
        }
        __syncthreads();

        unsigned p1 = s_prefix;
        for (int b = tid; b < 2048; b += 1024) hist[b] = 0;
        __syncthreads();
        for (int i = tid; i < NTOT / 4; i += 1024) {
            uint4 v = kb4[i];
            if (v.x && (v.x >> 21 << 21) == p1) atomicAdd(&hist[(v.x >> 10) & 2047], 1);
            if (v.y && (v.y >> 21 << 21) == p1) atomicAdd(&hist[(v.y >> 10) & 2047], 1);
            if (v.z && (v.z >> 21 << 21) == p1) atomicAdd(&hist[(v.z >> 10) & 2047], 1);
            if (v.w && (v.w >> 21 << 21) == p1) atomicAdd(&hist[(v.w >> 10) & 2047], 1);
        }
        __syncthreads();
        if (tid < 64) {
            int s = 0;
            for (int t = 0; t < 32; t++) s += hist[tid * 32 + t];
            gsum[tid] = s;
        }
        __syncthreads();
        if (tid == 0) {
            int r = s_rank;
            int g = 63;
            for (; g > 0; g--) { if (r <= gsum[g]) break; r -= gsum[g]; }
            int b = g * 32 + 31;
            for (; b > g * 32; b--) { if (r <= hist[b]) break; r -= hist[b]; }
            s_prefix = p1 | ((unsigned)b << 10);
            s_rank = r;
        }
        __syncthreads();

        unsigned p2 = s_prefix;
        for (int b = tid; b < 1024; b += 1024) hist[b] = 0;
        __syncthreads();
        for (int i = tid; i < NTOT / 4; i += 1024) {
            uint4 v = kb4[i];
            if (v.x && (v.x >> 10 << 10) == p2) atomicAdd(&hist[v.x & 1023], 1);
            if (v.y && (v.y >> 10 << 10) == p2) atomicAdd(&hist[v.y & 1023], 1);
            if (v.z && (v.z >> 10 << 10) == p2) atomicAdd(&hist[v.z & 1023], 1);
            if (v.w && (v.w >> 10 << 10) == p2) atomicAdd(&hist[v.w & 1023], 1);
        }
        __syncthreads();
        if (tid < 32) {
            int s = 0;
            for (int t = 0; t < 32; t++) s += hist[tid * 32 + t];
            gsum[tid] = s;
        }
        __syncthreads();
        if (tid == 0) {
            int r = s_rank;
            int g = 31;
            for (; g > 0; g--) { if (r <= gsum[g]) break; r -= gsum[g]; }
            int b = g * 32 + 31;
            for (; b > g * 32; b--) { if (r <= hist[b]) break; r -= hist[b]; }
            s_prefix = p2 | (unsigned)b;
        }
        __syncthreads();
    }

    if (tid == 0) {
        stats[0] = n_det;
        stats[1] = (n_det > DETS_PER_IMG) ? (int)s_prefix : 0;
    }
}

// ---------------- Kernel 5: final outputs ----------------
__global__ __launch_bounds__(256) void write_kernel(
    const unsigned* __restrict__ keepbits,
    const float4* __restrict__ dec,
    const int* __restrict__ stats,
    const int* __restrict__ ulabels,
    float* __restrict__ out)
{
    int i = blockIdx.x * blockDim.x + threadIdx.x;
    if (i >= NTOT) return;

    int n_det = stats[0];
    unsigned kth = (unsigned)stats[1];
    unsigned kb = keepbits[i];
    bool kf = kb && (n_det <= DETS_PER_IMG || kb >= kth);  // uint cmp == float cmp (positive)

    float4 b = dec[i];
    float* o5 = out + (size_t)i * 5;
    if (kf) {
        o5[0] = b.x; o5[1] = b.y; o5[2] = b.z; o5[3] = b.w;
        o5[4] = __uint_as_float(kb);
    } else {
        o5[0] = 0.0f; o5[1] = 0.0f; o5[2] = 0.0f; o5[3] = 0.0f; o5[4] = 0.0f;
    }

    int c = i >> 11;
    out[NTOT * 5 + i] = (float)ulabels[c];
    out[NTOT * 5 + NTOT + i] = kf ? 1.0f : 0.0f;
}

extern "C" void kernel_launch(void* const* d_in, const int* in_sizes, int n_in,
                              void* d_out, int out_size, void* d_ws, size_t ws_size,
                              hipStream_t stream) {
    (void)in_sizes; (void)n_in; (void)out_size; (void)ws_size;

    const float* class_logit    = (const float*)d_in[0];   // (NTOT,2)
    const float* box_regression = (const float*)d_in[1];   // (NTOT,8)
    const float* proposal_boxes = (const float*)d_in[2];   // (NBOX,4)
    const int*   unique_labels  = (const int*)d_in[3];     // (NCLS)

    char* ws = (char*)d_ws;
    float4* dec        = (float4*)(ws + 0);         // 524288
    u64* keys          = (u64*)(ws + 524288);       // 262144
    float4* sbox4      = (float4*)(ws + 786432);    // 524288
    float* sarea       = (float*)(ws + 1310720);    // 131072
    unsigned* keepbits = (unsigned*)(ws + 1441792); // 131072
    int* stats         = (int*)(ws + 1572864);      // 256
    u64* maskT         = (u64*)(ws + 1573120);      // 8388608

    float* out = (float*)d_out;

    sortdecode_kernel<<<NCLS, 1024, 0, stream>>>(class_logit, box_regression,
                                                 proposal_boxes, dec, keys,
                                                 sbox4, sarea);
    mask_kernel<<<NCLS * 16, 256, 0, stream>>>(sbox4, sarea, maskT);
    resolve_kernel<<<NCLS, 1024, 0, stream>>>(keys, maskT, keepbits);
    select_kernel<<<1, 1024, 0, stream>>>(keepbits, stats);
    write_kernel<<<NTOT / 256, 256, 0, stream>>>(keepbits, dec, stats,
                                                 unique_labels, out);
}